// Round 1
// baseline (4934.671 us; speedup 1.0000x reference)
//
#include <hip/hip_runtime.h>

#define NB 16   // batch
#define NA 6    // actions

// ---------------- weight gather: out[b,i] = w[i, action[b]] + bias[i] ----------------
__global__ void gen_weights(const float* __restrict__ w, const float* __restrict__ bias,
                            const int* __restrict__ action, float* __restrict__ out, int od) {
    int b = blockIdx.y;
    int a = action[b];
    for (int i = blockIdx.x * blockDim.x + threadIdx.x; i < od; i += gridDim.x * blockDim.x)
        out[(size_t)b * od + i] = w[(size_t)i * NA + a] + bias[i];
}

// ---------------- BN stats: per (b,c) mean/var over N pixels -> ga/be ----------------
__global__ void bn_stats(const float* __restrict__ z, const float* __restrict__ s,
                         const float* __restrict__ bvec, float* __restrict__ ga,
                         float* __restrict__ be, int Cc, int N) {
    int bc = blockIdx.x;
    int c = bc % Cc;
    const float* p = z + (size_t)bc * N;
    float sum = 0.f, sq = 0.f;
    for (int i = threadIdx.x * 4; i < N; i += blockDim.x * 4) {
        float4 v = *(const float4*)(p + i);
        sum += (v.x + v.y) + (v.z + v.w);
        sq  += (v.x * v.x + v.y * v.y) + (v.z * v.z + v.w * v.w);
    }
#pragma unroll
    for (int off = 32; off > 0; off >>= 1) {
        sum += __shfl_down(sum, off);
        sq  += __shfl_down(sq, off);
    }
    __shared__ float ssum[8], ssq[8];
    int wv = threadIdx.x >> 6;
    if ((threadIdx.x & 63) == 0) { ssum[wv] = sum; ssq[wv] = sq; }
    __syncthreads();
    if (threadIdx.x == 0) {
        float S = 0.f, Q = 0.f;
        int nw = blockDim.x >> 6;
        for (int i = 0; i < nw; ++i) { S += ssum[i]; Q += ssq[i]; }
        float inv = 1.f / (float)N;
        float m = S * inv;
        float var = Q * inv - m * m;
        float g = s[c] * rsqrtf(var + 1e-5f);
        ga[bc] = g;
        be[bc] = bvec[c] - m * g;
    }
}

// ---------------- BN apply (optionally ReLU), float4 vectorized ----------------
template<bool RELU>
__global__ void bn_apply(const float* __restrict__ in, float* __restrict__ out,
                         const float* __restrict__ ga, const float* __restrict__ be,
                         int shiftN, long total4) {
    long stride = (long)gridDim.x * blockDim.x;
    for (long i = (long)blockIdx.x * blockDim.x + threadIdx.x; i < total4; i += stride) {
        int bc = (int)((i << 2) >> shiftN);
        float g = ga[bc], b0 = be[bc];
        float4 v = ((const float4*)in)[i];
        v.x = v.x * g + b0; v.y = v.y * g + b0; v.z = v.z * g + b0; v.w = v.w * g + b0;
        if (RELU) {
            v.x = fmaxf(v.x, 0.f); v.y = fmaxf(v.y, 0.f);
            v.z = fmaxf(v.z, 0.f); v.w = fmaxf(v.w, 0.f);
        }
        ((float4*)out)[i] = v;
    }
}

// ---------------- direct 5x5 conv, 4 out-channels per thread ----------------
// in: [B, CIN, WH, WH]; wts: [B, COUT, CIN, 25]; out: [B, COUT, WH, WH]
template<int CIN, int DIL, int PAD, int WH>
__global__ void __launch_bounds__(256) conv5x5(const float* __restrict__ in,
                                               const float* __restrict__ wts,
                                               float* __restrict__ out, int COUT) {
    __shared__ __align__(16) float wf[CIN * 100];   // [CIN*25][4oc]
    const int b = blockIdx.z;
    const int og = blockIdx.y;                       // group of 4 out channels
    for (int idx = threadIdx.x; idx < CIN * 100; idx += 256) {
        int i = idx >> 2, oc = idx & 3;
        wf[idx] = wts[((size_t)(b * COUT + og * 4 + oc)) * (CIN * 25) + i];
    }
    __syncthreads();
    const int p = blockIdx.x * 256 + threadIdx.x;
    const int y = p / WH, x = p % WH;                // WH constexpr pow2 -> shifts
    const float* inb = in + (size_t)b * CIN * WH * WH;
    float a0 = 0.f, a1 = 0.f, a2 = 0.f, a3 = 0.f;
    for (int ci = 0; ci < CIN; ++ci) {
        const float* inc = inb + ci * WH * WH;
        const float4* w4p = (const float4*)wf + ci * 25;
#pragma unroll
        for (int ky = 0; ky < 5; ++ky) {
            const int iy = y + DIL * ky - PAD;
            const bool oky = (unsigned)iy < (unsigned)WH;
            const float* rowp = inc + iy * WH;
#pragma unroll
            for (int kx = 0; kx < 5; ++kx) {
                const int ix = x + DIL * kx - PAD;
                float v = (oky && (unsigned)ix < (unsigned)WH) ? rowp[ix] : 0.f;
                float4 w4 = w4p[ky * 5 + kx];
                a0 = fmaf(v, w4.x, a0); a1 = fmaf(v, w4.y, a1);
                a2 = fmaf(v, w4.z, a2); a3 = fmaf(v, w4.w, a3);
            }
        }
    }
    size_t ob = ((size_t)(b * COUT + og * 4)) * (WH * WH) + p;
    out[ob]               = a0;
    out[ob + WH * WH]     = a1;
    out[ob + 2 * WH * WH] = a2;
    out[ob + 3 * WH * WH] = a3;
}

// ---------------- 1x1 conv 64->4 @128^2 ----------------
__global__ void conv1x1(const float* __restrict__ in, const float* __restrict__ wts,
                        float* __restrict__ out) {
    __shared__ float w[256];
    const int b = blockIdx.z;
    w[threadIdx.x] = wts[b * 256 + threadIdx.x];
    __syncthreads();
    const int p = blockIdx.x * 256 + threadIdx.x;
    const float* inb = in + (size_t)b * 64 * 16384;
    float a0 = 0.f, a1 = 0.f, a2 = 0.f, a3 = 0.f;
#pragma unroll 8
    for (int ci = 0; ci < 64; ++ci) {
        float v = inb[ci * 16384 + p];
        a0 = fmaf(v, w[ci], a0);
        a1 = fmaf(v, w[64 + ci], a1);
        a2 = fmaf(v, w[128 + ci], a2);
        a3 = fmaf(v, w[192 + ci], a3);
    }
    size_t ob = (size_t)b * 4 * 16384 + p;
    out[ob] = a0; out[ob + 16384] = a1; out[ob + 32768] = a2; out[ob + 49152] = a3;
}

// ---------------- 2x2 avg pool: [64][256][256] -> [64*16384] flat per (b*c) ----------------
__global__ void avgpool2(const float* __restrict__ in, float* __restrict__ out, int total) {
    int stride = gridDim.x * blockDim.x;
    for (int i = blockIdx.x * blockDim.x + threadIdx.x; i < total; i += stride) {
        int wo = i & 127, ho = (i >> 7) & 127, bc = i >> 14;
        const float* p = in + ((size_t)bc << 16) + (ho << 9) + (wo << 1);
        out[i] = 0.25f * ((p[0] + p[1]) + (p[256] + p[257]));
    }
}

// ---------------- bilinear x2 (align_corners) from [B,4,128,128] + residual add ----------------
__global__ void up2_add(const float* __restrict__ h, const float* __restrict__ xin,
                        float* __restrict__ outp, int total) {
    int stride = gridDim.x * blockDim.x;
    const float sc = 127.f / 255.f;
    for (int i = blockIdx.x * blockDim.x + threadIdx.x; i < total; i += stride) {
        int xo = i & 255, yo = (i >> 8) & 255, bc = i >> 16;
        float px = xo * sc, py = yo * sc;
        int x0 = (int)px, y0 = (int)py;
        float fx = px - x0, fy = py - y0;
        int x1 = min(x0 + 1, 127), y1 = min(y0 + 1, 127);
        const float* hb = h + ((size_t)bc << 14);
        float v00 = hb[(y0 << 7) + x0], v01 = hb[(y0 << 7) + x1];
        float v10 = hb[(y1 << 7) + x0], v11 = hb[(y1 << 7) + x1];
        float vt = v00 + (v01 - v00) * fx;
        float vb = v10 + (v11 - v10) * fx;
        outp[i] = vt + (vb - vt) * fy + xin[i];
    }
}

extern "C" void kernel_launch(void* const* d_in, const int* in_sizes, int n_in,
                              void* d_out, int out_size, void* d_ws, size_t ws_size,
                              hipStream_t stream) {
    const float* x = (const float*)d_in[0];
    const int* action = (const int*)d_in[1];
    const float *W[7], *Bi[7], *bns[7], *bnb[7];
    for (int i = 0; i < 7; ++i) { W[i]   = (const float*)d_in[2 + 2 * i];
                                  Bi[i]  = (const float*)d_in[3 + 2 * i]; }
    for (int i = 0; i < 7; ++i) { bns[i] = (const float*)d_in[16 + 2 * i];
                                  bnb[i] = (const float*)d_in[17 + 2 * i]; }
    float* out = (float*)d_out;

    float* ws = (float*)d_ws;
    size_t off = 0;
    const int od[7] = {1600, 6400, 12800, 25600, 51200, 102400, 256};
    float* wb[7];
    for (int i = 0; i < 7; ++i) { wb[i] = ws + off; off += (size_t)od[i] * NB; }
    float* bufA = ws + off; off += 4194304;    // 16 MB: pool out / conv7 out
    float* bufB = ws + off; off += 16777216;   // 64 MB
    float* bufC = ws + off; off += 16777216;   // 64 MB
    float* ga   = ws + off; off += 1024;
    float* be   = ws + off; off += 1024;

    for (int i = 0; i < 7; ++i) {
        int gx = (od[i] + 255) / 256; if (gx > 64) gx = 64;
        gen_weights<<<dim3(gx, NB), 256, 0, stream>>>(W[i], Bi[i], action, wb[i], od[i]);
    }

    // bn0(x) -> d_out used as t0 (fully overwritten at the end)
    bn_stats<<<64, 512, 0, stream>>>(x, bns[0], bnb[0], ga, be, 4, 65536);
    bn_apply<false><<<2048, 256, 0, stream>>>(x, out, ga, be, 16, 1048576);

    // conv1: t0 -> bufB [16ch, 256^2]; bn1 + relu in place
    conv5x5<4, 2, 4, 256><<<dim3(256, 4, NB), 256, 0, stream>>>(out, wb[0], bufB, 16);
    bn_stats<<<256, 512, 0, stream>>>(bufB, bns[1], bnb[1], ga, be, 16, 65536);
    bn_apply<true><<<2048, 256, 0, stream>>>(bufB, bufB, ga, be, 16, 4194304);

    // conv2 -> bufC; bn2 in place
    conv5x5<16, 1, 2, 256><<<dim3(256, 4, NB), 256, 0, stream>>>(bufB, wb[1], bufC, 16);
    bn_stats<<<256, 512, 0, stream>>>(bufC, bns[2], bnb[2], ga, be, 16, 65536);
    bn_apply<false><<<2048, 256, 0, stream>>>(bufC, bufC, ga, be, 16, 4194304);

    // avgpool 2x2 -> bufA [16,16,128,128]
    avgpool2<<<2048, 256, 0, stream>>>(bufC, bufA, 4194304);

    // conv3 -> bufB [32ch, 128^2]; bn3 + relu
    conv5x5<16, 2, 4, 128><<<dim3(64, 8, NB), 256, 0, stream>>>(bufA, wb[2], bufB, 32);
    bn_stats<<<512, 512, 0, stream>>>(bufB, bns[3], bnb[3], ga, be, 32, 16384);
    bn_apply<true><<<2048, 256, 0, stream>>>(bufB, bufB, ga, be, 14, 2097152);

    // conv4 -> bufC; bn4
    conv5x5<32, 1, 2, 128><<<dim3(64, 8, NB), 256, 0, stream>>>(bufB, wb[3], bufC, 32);
    bn_stats<<<512, 512, 0, stream>>>(bufC, bns[4], bnb[4], ga, be, 32, 16384);
    bn_apply<false><<<2048, 256, 0, stream>>>(bufC, bufC, ga, be, 14, 2097152);

    // conv5 -> bufB [64ch, 128^2]; bn5 + relu
    conv5x5<32, 2, 4, 128><<<dim3(64, 16, NB), 256, 0, stream>>>(bufC, wb[4], bufB, 64);
    bn_stats<<<1024, 512, 0, stream>>>(bufB, bns[5], bnb[5], ga, be, 64, 16384);
    bn_apply<true><<<2048, 256, 0, stream>>>(bufB, bufB, ga, be, 14, 4194304);

    // conv6 -> bufC; bn6
    conv5x5<64, 1, 2, 128><<<dim3(64, 16, NB), 256, 0, stream>>>(bufB, wb[5], bufC, 64);
    bn_stats<<<1024, 512, 0, stream>>>(bufC, bns[6], bnb[6], ga, be, 64, 16384);
    bn_apply<false><<<2048, 256, 0, stream>>>(bufC, bufC, ga, be, 14, 4194304);

    // conv7 1x1 -> bufA [16,4,128,128]
    conv1x1<<<dim3(64, 1, NB), 256, 0, stream>>>(bufC, wb[6], bufA);

    // bilinear upsample x2 + residual -> d_out
    up2_add<<<4096, 256, 0, stream>>>(bufA, x, out, 4194304);
}

// Round 2
// 1297.501 us; speedup vs baseline: 3.8032x; 3.8032x over previous
//
#include <hip/hip_runtime.h>

#define NB 16   // batch
#define NA 6    // actions

typedef __attribute__((ext_vector_type(8))) short short8;
typedef __attribute__((ext_vector_type(4))) short short4_;
typedef __attribute__((ext_vector_type(4))) float f32x4;

__device__ __forceinline__ short tobf(float f) {
    unsigned u = __builtin_bit_cast(unsigned, f);
    u += 0x7FFF + ((u >> 16) & 1);
    return (short)(u >> 16);
}
__device__ __forceinline__ float frombf(short s) {
    unsigned u = ((unsigned)(unsigned short)s) << 16;
    return __builtin_bit_cast(float, u);
}

// ---------------- weight gather (fp32, conv1/conv7): out[b,i] = w[i, action[b]] + bias[i] ----------------
__global__ void gen_weights(const float* __restrict__ w, const float* __restrict__ bias,
                            const int* __restrict__ action, float* __restrict__ out, int od) {
    int b = blockIdx.y;
    int a = action[b];
    for (int i = blockIdx.x * blockDim.x + threadIdx.x; i < od; i += gridDim.x * blockDim.x)
        out[(size_t)b * od + i] = w[(size_t)i * NA + a] + bias[i];
}

// ---------------- weight gather+pack to bf16 A-fragment layout [b][Kpad/8][COUT][8] ----------------
// k = pos*CIN + ci, pos = ky*5+kx; zero-pad k >= 25*CIN
template<int CIN, int COUT>
__global__ void pack_w(const float* __restrict__ w, const float* __restrict__ bias,
                       const int* __restrict__ action, short* __restrict__ dst) {
    constexpr int KTOT = 25 * CIN;
    constexpr int KPAD = (KTOT + 31) & ~31;
    int b = blockIdx.y;
    int a = action[b];
    for (int j = blockIdx.x * 256 + threadIdx.x; j < COUT * KPAD; j += gridDim.x * 256) {
        int oc = j / KPAD, k = j - oc * KPAD;
        float v = 0.f;
        if (k < KTOT) {
            int pos = k / CIN, ci = k - pos * CIN;
            int ky = pos / 5, kx = pos - ky * 5;
            int od = ((oc * CIN + ci) * 5 + ky) * 5 + kx;
            v = w[(size_t)od * NA + a] + bias[od];
        }
        dst[((size_t)(b * (KPAD / 8) + (k >> 3)) * COUT + oc) * 8 + (k & 7)] = tobf(v);
    }
}

// ---------------- BN stats for bn0 (NCHW input x) ----------------
__global__ void bn_stats(const float* __restrict__ z, const float* __restrict__ s,
                         const float* __restrict__ bvec, float* __restrict__ ga,
                         float* __restrict__ be, int Cc, int N) {
    int bc = blockIdx.x;
    int c = bc % Cc;
    const float* p = z + (size_t)bc * N;
    float sum = 0.f, sq = 0.f;
    for (int i = threadIdx.x * 4; i < N; i += blockDim.x * 4) {
        float4 v = *(const float4*)(p + i);
        sum += (v.x + v.y) + (v.z + v.w);
        sq  += (v.x * v.x + v.y * v.y) + (v.z * v.z + v.w * v.w);
    }
#pragma unroll
    for (int off = 32; off > 0; off >>= 1) {
        sum += __shfl_down(sum, off);
        sq  += __shfl_down(sq, off);
    }
    __shared__ float ssum[8], ssq[8];
    int wv = threadIdx.x >> 6;
    if ((threadIdx.x & 63) == 0) { ssum[wv] = sum; ssq[wv] = sq; }
    __syncthreads();
    if (threadIdx.x == 0) {
        float S = 0.f, Q = 0.f;
        int nw = blockDim.x >> 6;
        for (int i = 0; i < nw; ++i) { S += ssum[i]; Q += ssq[i]; }
        float inv = 1.f / (float)N;
        float m = S * inv;
        float var = Q * inv - m * m;
        float g = s[c] * rsqrtf(var + 1e-5f);
        ga[bc] = g;
        be[bc] = bvec[c] - m * g;
    }
}

// ---------------- bn0 apply: x NCHW fp32 -> a0 NHWC bf16 (C=4) ----------------
__global__ void bn0_apply(const float* __restrict__ x, short* __restrict__ a0,
                          const float* __restrict__ ga, const float* __restrict__ be) {
    int t = blockIdx.x * 256 + threadIdx.x;   // 16*65536 threads
    int b = t >> 16, px = t & 65535;
    f32x4 g = *(const f32x4*)&ga[b * 4];
    f32x4 e = *(const f32x4*)&be[b * 4];
    short4_ o;
#pragma unroll
    for (int c = 0; c < 4; ++c) {
        float v = x[(((size_t)b * 4 + c) << 16) + px];
        o[c] = tobf(v * g[c] + e[c]);
    }
    *(short4_*)&a0[((size_t)t) * 4] = o;
}

// ---------------- conv1: direct fp32, 4px x 16oc per thread; a0 NHWC bf16 -> c1 NHWC fp32 ----------------
__global__ void __launch_bounds__(256) conv1k(const short* __restrict__ a0,
                                              const float* __restrict__ w1g,
                                              float* __restrict__ c1) {
    __shared__ float wf[1600];   // [pos25][ci4][oc16]
    const int b = blockIdx.y;
    for (int t = threadIdx.x; t < 1600; t += 256) {
        int pos = t / 64, ci = (t >> 4) & 3, oc = t & 15;
        wf[t] = w1g[b * 1600 + (oc * 4 + ci) * 25 + pos];
    }
    __syncthreads();
    const int y = blockIdx.x * 4 + (threadIdx.x >> 6);
    const int xb = (threadIdx.x & 63) * 4;
    const short* ab = a0 + ((size_t)b << 18);   // *65536*4
    f32x4 acc[4][4] = {};
#pragma unroll
    for (int ky = 0; ky < 5; ++ky) {
        int gy = y + 2 * ky - 4;
        bool oky = (unsigned)gy < 256u;
        short4_ seg[12];
#pragma unroll
        for (int j = 0; j < 12; ++j) {
            int gx = xb - 4 + j;
            if (oky && (unsigned)gx < 256u) seg[j] = *(const short4_*)&ab[(((size_t)gy << 8) + gx) << 2];
            else seg[j] = short4_{0, 0, 0, 0};
        }
#pragma unroll
        for (int kx = 0; kx < 5; ++kx) {
            int pos = ky * 5 + kx;
#pragma unroll
            for (int ci = 0; ci < 4; ++ci) {
                f32x4 w0 = *(const f32x4*)&wf[(pos * 4 + ci) * 16];
                f32x4 w1 = *(const f32x4*)&wf[(pos * 4 + ci) * 16 + 4];
                f32x4 w2 = *(const f32x4*)&wf[(pos * 4 + ci) * 16 + 8];
                f32x4 w3 = *(const f32x4*)&wf[(pos * 4 + ci) * 16 + 12];
#pragma unroll
                for (int pxi = 0; pxi < 4; ++pxi) {
                    float f = frombf(seg[2 * kx + pxi][ci]);
                    acc[pxi][0] += w0 * f; acc[pxi][1] += w1 * f;
                    acc[pxi][2] += w2 * f; acc[pxi][3] += w3 * f;
                }
            }
        }
    }
#pragma unroll
    for (int pxi = 0; pxi < 4; ++pxi) {
        size_t ob = ((size_t)b * 65536 + y * 256 + xb + pxi) * 16;
#pragma unroll
        for (int o = 0; o < 4; ++o) *(f32x4*)&c1[ob + o * 4] = acc[pxi][o];
    }
}

// ---------------- MFMA 5x5 conv: in NHWC bf16 -> out NHWC fp32 ----------------
template<int CIN, int COUT, int DIL, int WH, int PXB>
__global__ void __launch_bounds__(256) convmf(const short* __restrict__ in,
                                              const short* __restrict__ wpack,
                                              float* __restrict__ outp) {
    constexpr int PAD  = 2 * DIL;
    constexpr int XT   = PXB + 4 * DIL + 1;
    constexpr int KTOT = 25 * CIN;
    constexpr int KPAD = (KTOT + 31) & ~31;
    constexpr int NSTEP = KPAD / 32;
    constexpr int CINB = CIN / 8;
    constexpr int S    = (CIN == 64) ? 0 : (CIN == 32) ? 1 : 2;   // swizzle shift
    constexpr int LC   = (CIN == 64) ? 6 : (CIN == 32) ? 5 : 4;   // log2(CIN)
    constexpr int OT   = (COUT == 64) ? 2 : 1;
    constexpr int PT   = (COUT == 16) ? 4 : 2;

    __shared__ short T[5 * XT * CIN];

    const int b  = blockIdx.z;
    const int y  = blockIdx.y;
    const int x0 = blockIdx.x * PXB;
    const int tid = threadIdx.x;
    const short* inb = in + (size_t)b * WH * WH * CIN;

    // stage 5 dilated rows x XT cols x CIN channels, ci-chunk XOR swizzle
    for (int idx = tid; idx < 5 * XT * CINB; idx += 256) {
        int dyi = idx / (XT * CINB);
        int rem = idx - dyi * (XT * CINB);
        int xl = rem / CINB, cic = rem - xl * CINB;
        int gy = y + DIL * dyi - PAD;
        int gx = x0 - PAD + xl;
        short8 v = {0, 0, 0, 0, 0, 0, 0, 0};
        if ((unsigned)gy < (unsigned)WH && (unsigned)gx < (unsigned)WH)
            v = *(const short8*)&inb[((size_t)gy * WH + gx) * CIN + cic * 8];
        int r = dyi * XT + xl;
        int cs = (cic ^ ((r >> S) & (CINB - 1))) << 3;
        *(short8*)&T[r * CIN + cs] = v;
    }
    __syncthreads();

    const int w = tid >> 6, lane = tid & 63;
    const int l15 = lane & 15, loct = lane >> 4;
    int pxbase, ocbase;
    if (COUT == 16) { pxbase = w * 64; ocbase = 0; }
    else            { pxbase = (w >> 1) * 32; ocbase = (w & 1) * (OT * 16); }

    const short* wpb = wpack + (size_t)b * KPAD * COUT;
    f32x4 acc[OT][PT] = {};

    short8 A[OT];
    {
        size_t o = ((size_t)loct * COUT + ocbase + l15) * 8;
#pragma unroll
        for (int ot = 0; ot < OT; ++ot) A[ot] = *(const short8*)&wpb[o + ot * 128];
    }
    for (int s = 0; s < NSTEP; ++s) {
        short8 An[OT];
        if (s + 1 < NSTEP) {
            size_t o = ((size_t)((s + 1) * 4 + loct) * COUT + ocbase + l15) * 8;
#pragma unroll
            for (int ot = 0; ot < OT; ++ot) An[ot] = *(const short8*)&wpb[o + ot * 128];
        }
        int kq = s * 32 + (loct << 3);
        int pos = kq >> LC;
        if (pos > 24) pos = 24;                 // padded k: weights are zero
        int cic = (kq & (CIN - 1)) >> 3;
        int ky = pos / 5, kx = pos - ky * 5;
        int r = ky * XT + pxbase + l15 + kx * DIL;
        int cs = (cic ^ ((r >> S) & (CINB - 1))) << 3;
        int ba = r * CIN + cs;
        short8 Bv[PT];
#pragma unroll
        for (int pt = 0; pt < PT; ++pt) Bv[pt] = *(const short8*)&T[ba + pt * 16 * CIN];
#pragma unroll
        for (int ot = 0; ot < OT; ++ot)
#pragma unroll
            for (int pt = 0; pt < PT; ++pt)
                acc[ot][pt] = __builtin_amdgcn_mfma_f32_16x16x32_bf16(A[ot], Bv[pt], acc[ot][pt], 0, 0, 0);
#pragma unroll
        for (int ot = 0; ot < OT; ++ot) A[ot] = An[ot];
    }

#pragma unroll
    for (int ot = 0; ot < OT; ++ot)
#pragma unroll
        for (int pt = 0; pt < PT; ++pt) {
            int gpx = y * WH + x0 + pxbase + pt * 16 + l15;
            int oc = ocbase + ot * 16 + (loct << 2);
            *(f32x4*)&outp[((size_t)b * WH * WH + gpx) * COUT + oc] = acc[ot][pt];
        }
}

// ---------------- BN stats partials over NHWC fp32: part[b][32][2][C] ----------------
template<int C>
__global__ void stats_part(const float* __restrict__ z, float* __restrict__ part, int HW) {
    constexpr int C4 = C / 4;
    const int slice = blockIdx.x, b = blockIdx.y;
    const int PS = HW / 32;
    const int t = threadIdx.x;
    const int oc4 = t & (C4 - 1);
    f32x4 s4 = {0.f, 0.f, 0.f, 0.f}, q4 = {0.f, 0.f, 0.f, 0.f};
    for (int px = slice * PS + t / C4; px < (slice + 1) * PS; px += 256 / C4) {
        f32x4 v = *(const f32x4*)&z[((size_t)b * HW + px) * C + oc4 * 4];
        s4 += v; q4 += v * v;
    }
    __shared__ f32x4 ss[256], sq[256];
    ss[t] = s4; sq[t] = q4;
    __syncthreads();
    for (int off = 128; off >= C4; off >>= 1) {
        if (t < off) { ss[t] += ss[t + off]; sq[t] += sq[t + off]; }
        __syncthreads();
    }
    if (t < C4) {
        *(f32x4*)&part[((size_t)(b * 32 + slice) * 2 + 0) * C + t * 4] = ss[t];
        *(f32x4*)&part[((size_t)(b * 32 + slice) * 2 + 1) * C + t * 4] = sq[t];
    }
}

template<int C>
__global__ void stats_fin(const float* __restrict__ part, const float* __restrict__ s,
                          const float* __restrict__ bvec, float* __restrict__ ga,
                          float* __restrict__ be, int N) {
    int b = blockIdx.x, c = threadIdx.x;
    float S = 0.f, Q = 0.f;
    for (int j = 0; j < 32; ++j) {
        S += part[((size_t)(b * 32 + j) * 2 + 0) * C + c];
        Q += part[((size_t)(b * 32 + j) * 2 + 1) * C + c];
    }
    float inv = 1.f / (float)N;
    float m = S * inv;
    float var = Q * inv - m * m;
    float g = s[c] * rsqrtf(var + 1e-5f);
    ga[b * C + c] = g;
    be[b * C + c] = bvec[c] - m * g;
}

// ---------------- BN apply NHWC fp32 -> NHWC bf16 (optional ReLU) ----------------
template<int C, bool RELU>
__global__ void bn_apply_nhwc(const float* __restrict__ in, short* __restrict__ out,
                              const float* __restrict__ ga, const float* __restrict__ be,
                              int HW) {
    constexpr int C4 = C / 4;
    long total4 = (long)NB * HW * C4;
    long stride = (long)gridDim.x * blockDim.x;
    for (long i = (long)blockIdx.x * blockDim.x + threadIdx.x; i < total4; i += stride) {
        int c4 = (int)(i % C4);
        int b = (int)(i / ((long)HW * C4));
        f32x4 g = *(const f32x4*)&ga[b * C + c4 * 4];
        f32x4 e = *(const f32x4*)&be[b * C + c4 * 4];
        f32x4 v = *(const f32x4*)&in[i * 4];
        v = v * g + e;
        short4_ o;
#pragma unroll
        for (int j = 0; j < 4; ++j) {
            float f = v[j];
            if (RELU) f = fmaxf(f, 0.f);
            o[j] = tobf(f);
        }
        *(short4_*)&out[i * 4] = o;
    }
}

// ---------------- bn2 apply + 2x2 avgpool: c2 [B][65536][16] fp32 -> a2p [B][16384][16] bf16 ----------------
__global__ void bnpool(const float* __restrict__ in, short* __restrict__ out,
                       const float* __restrict__ ga, const float* __restrict__ be) {
    int t = blockIdx.x * 256 + threadIdx.x;   // 16*16384*4
    int c4 = t & 3, wo = (t >> 2) & 127, ho = (t >> 9) & 127, b = t >> 16;
    size_t pi = ((size_t)b * 65536 + (ho * 2) * 256 + wo * 2) * 16 + c4 * 4;
    f32x4 v = *(const f32x4*)&in[pi];
    v += *(const f32x4*)&in[pi + 16];
    v += *(const f32x4*)&in[pi + 4096];
    v += *(const f32x4*)&in[pi + 4112];
    f32x4 g = *(const f32x4*)&ga[b * 16 + c4 * 4];
    f32x4 e = *(const f32x4*)&be[b * 16 + c4 * 4];
    v = v * 0.25f * g + e;
    short4_ o;
#pragma unroll
    for (int j = 0; j < 4; ++j) o[j] = tobf(v[j]);
    *(short4_*)&out[((size_t)b * 16384 + ho * 128 + wo) * 16 + c4 * 4] = o;
}

// ---------------- conv7 1x1 64->4: a6 NHWC bf16 -> c7 NHWC fp32 [B][16384][4] ----------------
__global__ void conv7k(const short* __restrict__ a6, const float* __restrict__ w7g,
                       float* __restrict__ c7) {
    __shared__ float wsm[256];
    const int b = blockIdx.y;
    wsm[threadIdx.x] = w7g[b * 256 + threadIdx.x];
    __syncthreads();
    const int t = threadIdx.x;
    const int px = blockIdx.x * 64 + (t >> 2);
    const int part = t & 3;
    size_t base = ((size_t)b * 16384 + px) * 64 + part * 16;
    short8 s0 = *(const short8*)&a6[base];
    short8 s1 = *(const short8*)&a6[base + 8];
    f32x4 a = {0.f, 0.f, 0.f, 0.f};
#pragma unroll
    for (int ci = 0; ci < 8; ++ci) {
        float f0 = frombf(s0[ci]), f1 = frombf(s1[ci]);
#pragma unroll
        for (int o = 0; o < 4; ++o) {
            a[o] = fmaf(f0, wsm[o * 64 + part * 16 + ci], a[o]);
            a[o] = fmaf(f1, wsm[o * 64 + part * 16 + 8 + ci], a[o]);
        }
    }
#pragma unroll
    for (int o = 0; o < 4; ++o) {
        a[o] += __shfl_xor(a[o], 1);
        a[o] += __shfl_xor(a[o], 2);
    }
    if (part == 0) *(f32x4*)&c7[((size_t)b * 16384 + px) * 4] = a;
}

// ---------------- bilinear x2 (align_corners) from NHWC [B,128,128,4] + residual -> NCHW out ----------------
__global__ void up2_add(const float* __restrict__ h, const float* __restrict__ xin,
                        float* __restrict__ outp, int total) {
    int stride = gridDim.x * blockDim.x;
    const float sc = 127.f / 255.f;
    for (int i = blockIdx.x * blockDim.x + threadIdx.x; i < total; i += stride) {
        int xo = i & 255, yo = (i >> 8) & 255, c = (i >> 16) & 3, b = i >> 18;
        float px = xo * sc, py = yo * sc;
        int x0 = (int)px, y0 = (int)py;
        float fx = px - x0, fy = py - y0;
        int x1 = min(x0 + 1, 127), y1 = min(y0 + 1, 127);
        const float* hb = h + ((size_t)b << 16);
        float v00 = hb[((y0 << 7) + x0) * 4 + c], v01 = hb[((y0 << 7) + x1) * 4 + c];
        float v10 = hb[((y1 << 7) + x0) * 4 + c], v11 = hb[((y1 << 7) + x1) * 4 + c];
        float vt = v00 + (v01 - v00) * fx;
        float vb = v10 + (v11 - v10) * fx;
        outp[i] = vt + (vb - vt) * fy + xin[i];
    }
}

extern "C" void kernel_launch(void* const* d_in, const int* in_sizes, int n_in,
                              void* d_out, int out_size, void* d_ws, size_t ws_size,
                              hipStream_t stream) {
    const float* x = (const float*)d_in[0];
    const int* action = (const int*)d_in[1];
    const float *W[7], *Bi[7], *bns[7], *bnb[7];
    for (int i = 0; i < 7; ++i) { W[i]   = (const float*)d_in[2 + 2 * i];
                                  Bi[i]  = (const float*)d_in[3 + 2 * i]; }
    for (int i = 0; i < 7; ++i) { bns[i] = (const float*)d_in[16 + 2 * i];
                                  bnb[i] = (const float*)d_in[17 + 2 * i]; }
    float* out = (float*)d_out;

    // ---- workspace carve (bytes) ----
    char* p = (char*)d_ws;
    auto carve = [&](size_t bytes) { char* r = p; p += (bytes + 255) & ~(size_t)255; return r; };
    float* w1g  = (float*)carve(1600 * NB * 4);
    float* w7g  = (float*)carve(256 * NB * 4);
    float* ga   = (float*)carve(1024 * 4);
    float* be   = (float*)carve(1024 * 4);
    float* part = (float*)carve(16 * 32 * 2 * 64 * 4);
    short* wp2  = (short*)carve((size_t)416 * 16 * NB * 2);
    short* wp3  = (short*)carve((size_t)416 * 32 * NB * 2);
    short* wp4  = (short*)carve((size_t)800 * 32 * NB * 2);
    short* wp5  = (short*)carve((size_t)800 * 64 * NB * 2);
    short* wp6  = (short*)carve((size_t)1600 * 64 * NB * 2);
    float* CBUF = (float*)carve((size_t)NB * 65536 * 16 * 4);   // 67 MB: every conv out (fp32)
    short* AB0  = (short*)carve((size_t)NB * 16384 * 64 * 2);   // a0/a2p/a4/a6
    short* AB1  = (short*)carve((size_t)NB * 65536 * 16 * 2);   // a1/a3/a5

    // ---- weights ----
    gen_weights<<<dim3(7, NB), 256, 0, stream>>>(W[0], Bi[0], action, w1g, 1600);
    gen_weights<<<dim3(1, NB), 256, 0, stream>>>(W[6], Bi[6], action, w7g, 256);
    pack_w<16, 16><<<dim3(26, NB),  256, 0, stream>>>(W[1], Bi[1], action, wp2);
    pack_w<16, 32><<<dim3(52, NB),  256, 0, stream>>>(W[2], Bi[2], action, wp3);
    pack_w<32, 32><<<dim3(100, NB), 256, 0, stream>>>(W[3], Bi[3], action, wp4);
    pack_w<32, 64><<<dim3(200, NB), 256, 0, stream>>>(W[4], Bi[4], action, wp5);
    pack_w<64, 64><<<dim3(400, NB), 256, 0, stream>>>(W[5], Bi[5], action, wp6);

    // ---- bn0 -> a0 (NHWC bf16, C=4) ----
    bn_stats<<<64, 512, 0, stream>>>(x, bns[0], bnb[0], ga, be, 4, 65536);
    bn0_apply<<<4096, 256, 0, stream>>>(x, AB0, ga, be);

    // ---- conv1 -> CBUF; bn1+relu -> a1 ----
    conv1k<<<dim3(64, NB), 256, 0, stream>>>(AB0, w1g, CBUF);
    stats_part<16><<<dim3(32, NB), 256, 0, stream>>>(CBUF, part, 65536);
    stats_fin<16><<<NB, 16, 0, stream>>>(part, bns[1], bnb[1], ga, be, 65536);
    bn_apply_nhwc<16, true><<<2048, 256, 0, stream>>>(CBUF, AB1, ga, be, 65536);

    // ---- conv2 -> CBUF; bn2 + avgpool -> a2p ----
    convmf<16, 16, 1, 256, 256><<<dim3(1, 256, NB), 256, 0, stream>>>(AB1, wp2, CBUF);
    stats_part<16><<<dim3(32, NB), 256, 0, stream>>>(CBUF, part, 65536);
    stats_fin<16><<<NB, 16, 0, stream>>>(part, bns[2], bnb[2], ga, be, 65536);
    bnpool<<<4096, 256, 0, stream>>>(CBUF, AB0, ga, be);

    // ---- conv3 -> CBUF; bn3+relu -> a3 ----
    convmf<16, 32, 2, 128, 64><<<dim3(2, 128, NB), 256, 0, stream>>>(AB0, wp3, CBUF);
    stats_part<32><<<dim3(32, NB), 256, 0, stream>>>(CBUF, part, 16384);
    stats_fin<32><<<NB, 32, 0, stream>>>(part, bns[3], bnb[3], ga, be, 16384);
    bn_apply_nhwc<32, true><<<2048, 256, 0, stream>>>(CBUF, AB1, ga, be, 16384);

    // ---- conv4 -> CBUF; bn4 -> a4 ----
    convmf<32, 32, 1, 128, 64><<<dim3(2, 128, NB), 256, 0, stream>>>(AB1, wp4, CBUF);
    stats_part<32><<<dim3(32, NB), 256, 0, stream>>>(CBUF, part, 16384);
    stats_fin<32><<<NB, 32, 0, stream>>>(part, bns[4], bnb[4], ga, be, 16384);
    bn_apply_nhwc<32, false><<<2048, 256, 0, stream>>>(CBUF, AB0, ga, be, 16384);

    // ---- conv5 -> CBUF; bn5+relu -> a5 ----
    convmf<32, 64, 2, 128, 64><<<dim3(2, 128, NB), 256, 0, stream>>>(AB0, wp5, CBUF);
    stats_part<64><<<dim3(32, NB), 256, 0, stream>>>(CBUF, part, 16384);
    stats_fin<64><<<NB, 64, 0, stream>>>(part, bns[5], bnb[5], ga, be, 16384);
    bn_apply_nhwc<64, true><<<2048, 256, 0, stream>>>(CBUF, AB1, ga, be, 16384);

    // ---- conv6 -> CBUF; bn6 -> a6 ----
    convmf<64, 64, 1, 128, 64><<<dim3(2, 128, NB), 256, 0, stream>>>(AB1, wp6, CBUF);
    stats_part<64><<<dim3(32, NB), 256, 0, stream>>>(CBUF, part, 16384);
    stats_fin<64><<<NB, 64, 0, stream>>>(part, bns[6], bnb[6], ga, be, 16384);
    bn_apply_nhwc<64, false><<<2048, 256, 0, stream>>>(CBUF, AB0, ga, be, 16384);

    // ---- conv7 -> CBUF (reused); up2 + residual -> out ----
    conv7k<<<dim3(256, NB), 256, 0, stream>>>(AB0, w7g, CBUF);
    up2_add<<<4096, 256, 0, stream>>>(CBUF, x, out, 4194304);
}

// Round 3
// 526.661 us; speedup vs baseline: 9.3697x; 2.4636x over previous
//
#include <hip/hip_runtime.h>

#define NB 16   // batch
#define NA 6    // actions

typedef __attribute__((ext_vector_type(8))) short short8;
typedef __attribute__((ext_vector_type(4))) short short4_;
typedef __attribute__((ext_vector_type(4))) float f32x4;

__device__ __forceinline__ short tobf(float f) {
    unsigned u = __builtin_bit_cast(unsigned, f);
    u += 0x7FFF + ((u >> 16) & 1);
    return (short)(u >> 16);
}
__device__ __forceinline__ float frombf(short s) {
    unsigned u = ((unsigned)(unsigned short)s) << 16;
    return __builtin_bit_cast(float, u);
}

// ---------------- weight gather (fp32, conv1/conv7): out[b,i] = w[i, action[b]] + bias[i] ----------------
__global__ void gen_weights(const float* __restrict__ w, const float* __restrict__ bias,
                            const int* __restrict__ action, float* __restrict__ out, int od) {
    int b = blockIdx.y;
    int a = action[b];
    for (int i = blockIdx.x * blockDim.x + threadIdx.x; i < od; i += gridDim.x * blockDim.x)
        out[(size_t)b * od + i] = w[(size_t)i * NA + a] + bias[i];
}

// ---------------- weight gather+pack to bf16 A-fragment layout [b][Kpad/8][COUT][8] ----------------
// k = pos*CIN + ci, pos = ky*5+kx; zero-pad k >= 25*CIN
template<int CIN, int COUT>
__global__ void pack_w(const float* __restrict__ w, const float* __restrict__ bias,
                       const int* __restrict__ action, short* __restrict__ dst) {
    constexpr int KTOT = 25 * CIN;
    constexpr int KPAD = (KTOT + 31) & ~31;
    int b = blockIdx.y;
    int a = action[b];
    for (int j = blockIdx.x * 256 + threadIdx.x; j < COUT * KPAD; j += gridDim.x * 256) {
        int oc = j / KPAD, k = j - oc * KPAD;
        float v = 0.f;
        if (k < KTOT) {
            int pos = k / CIN, ci = k - pos * CIN;
            int ky = pos / 5, kx = pos - ky * 5;
            int od = ((oc * CIN + ci) * 5 + ky) * 5 + kx;
            v = w[(size_t)od * NA + a] + bias[od];
        }
        dst[((size_t)(b * (KPAD / 8) + (k >> 3)) * COUT + oc) * 8 + (k & 7)] = tobf(v);
    }
}

// ---------------- BN stats for bn0 (NCHW input x) ----------------
__global__ void bn_stats(const float* __restrict__ z, const float* __restrict__ s,
                         const float* __restrict__ bvec, float* __restrict__ ga,
                         float* __restrict__ be, int Cc, int N) {
    int bc = blockIdx.x;
    int c = bc % Cc;
    const float* p = z + (size_t)bc * N;
    float sum = 0.f, sq = 0.f;
    for (int i = threadIdx.x * 4; i < N; i += blockDim.x * 4) {
        float4 v = *(const float4*)(p + i);
        sum += (v.x + v.y) + (v.z + v.w);
        sq  += (v.x * v.x + v.y * v.y) + (v.z * v.z + v.w * v.w);
    }
#pragma unroll
    for (int off = 32; off > 0; off >>= 1) {
        sum += __shfl_down(sum, off);
        sq  += __shfl_down(sq, off);
    }
    __shared__ float ssum[8], ssq[8];
    int wv = threadIdx.x >> 6;
    if ((threadIdx.x & 63) == 0) { ssum[wv] = sum; ssq[wv] = sq; }
    __syncthreads();
    if (threadIdx.x == 0) {
        float S = 0.f, Q = 0.f;
        int nw = blockDim.x >> 6;
        for (int i = 0; i < nw; ++i) { S += ssum[i]; Q += ssq[i]; }
        float inv = 1.f / (float)N;
        float m = S * inv;
        float var = Q * inv - m * m;
        float g = s[c] * rsqrtf(var + 1e-5f);
        ga[bc] = g;
        be[bc] = bvec[c] - m * g;
    }
}

// ---------------- bn0 apply: x NCHW fp32 -> a0 NHWC bf16 (C=4) ----------------
__global__ void bn0_apply(const float* __restrict__ x, short* __restrict__ a0,
                          const float* __restrict__ ga, const float* __restrict__ be) {
    int t = blockIdx.x * 256 + threadIdx.x;   // 16*65536 threads
    int b = t >> 16, px = t & 65535;
    f32x4 g = *(const f32x4*)&ga[b * 4];
    f32x4 e = *(const f32x4*)&be[b * 4];
    short4_ o;
#pragma unroll
    for (int c = 0; c < 4; ++c) {
        float v = x[(((size_t)b * 4 + c) << 16) + px];
        o[c] = tobf(v * g[c] + e[c]);
    }
    *(short4_*)&a0[((size_t)t) * 4] = o;
}

// ---------------- conv1: one px/thread, 16 oc; LDS halo tile; a0 NHWC bf16 -> c1 NHWC fp32 ----------------
__global__ void __launch_bounds__(256) conv1k(const short* __restrict__ a0,
                                              const float* __restrict__ w1g,
                                              float* __restrict__ c1) {
    __shared__ float wf[1600];          // [pos25][ci4][oc16]
    __shared__ short4_ tile[12 * 72];   // 12 halo rows x 72 halo cols, 8B/px
    const int b = blockIdx.z;
    const int y0 = blockIdx.y * 4;
    const int x0 = blockIdx.x * 64;
    const int tid = threadIdx.x;
    for (int t = tid; t < 1600; t += 256) {
        int pos = t >> 6, ci = (t >> 4) & 3, oc = t & 15;
        wf[t] = w1g[b * 1600 + (oc * 4 + ci) * 25 + pos];
    }
    const short* ab = a0 + ((size_t)b << 18);   // *65536*4
    for (int idx = tid; idx < 12 * 72; idx += 256) {
        int r = idx / 72, cl = idx - r * 72;
        int gy = y0 - 4 + r, gx = x0 - 4 + cl;
        short4_ v = {0, 0, 0, 0};
        if ((unsigned)gy < 256u && (unsigned)gx < 256u)
            v = *(const short4_*)&ab[(((size_t)gy << 8) + gx) << 2];
        tile[idx] = v;
    }
    __syncthreads();
    const int yr = tid >> 6, xc = tid & 63;
    f32x4 acc[4] = {};
#pragma unroll
    for (int ky = 0; ky < 5; ++ky) {
#pragma unroll
        for (int kx = 0; kx < 5; ++kx) {
            short4_ s = tile[(yr + 2 * ky) * 72 + xc + 2 * kx];
            const int pos = ky * 5 + kx;
#pragma unroll
            for (int ci = 0; ci < 4; ++ci) {
                float f = frombf(s[ci]);
                const float* wp = &wf[(pos * 4 + ci) * 16];
#pragma unroll
                for (int o = 0; o < 4; ++o)
                    acc[o] += *(const f32x4*)(wp + o * 4) * f;
            }
        }
    }
    size_t ob = ((size_t)b * 65536 + (size_t)(y0 + yr) * 256 + x0 + xc) * 16;
#pragma unroll
    for (int o = 0; o < 4; ++o) *(f32x4*)&c1[ob + o * 4] = acc[o];
}

// ---------------- MFMA 5x5 conv: in NHWC bf16 -> out NHWC fp32 ----------------
template<int CIN, int COUT, int DIL, int WH, int PXB>
__global__ void __launch_bounds__(256) convmf(const short* __restrict__ in,
                                              const short* __restrict__ wpack,
                                              float* __restrict__ outp) {
    constexpr int PAD  = 2 * DIL;
    constexpr int XT   = PXB + 4 * DIL + 1;
    constexpr int KTOT = 25 * CIN;
    constexpr int KPAD = (KTOT + 31) & ~31;
    constexpr int NSTEP = KPAD / 32;
    constexpr int CINB = CIN / 8;
    constexpr int S    = (CIN == 64) ? 0 : (CIN == 32) ? 1 : 2;   // swizzle shift
    constexpr int LC   = (CIN == 64) ? 6 : (CIN == 32) ? 5 : 4;   // log2(CIN)
    constexpr int OT   = (COUT == 64) ? 2 : 1;
    constexpr int PT   = (COUT == 16) ? 4 : 2;

    __shared__ short T[5 * XT * CIN];

    const int b  = blockIdx.z;
    const int y  = blockIdx.y;
    const int x0 = blockIdx.x * PXB;
    const int tid = threadIdx.x;
    const short* inb = in + (size_t)b * WH * WH * CIN;

    // stage 5 dilated rows x XT cols x CIN channels, ci-chunk XOR swizzle
    for (int idx = tid; idx < 5 * XT * CINB; idx += 256) {
        int dyi = idx / (XT * CINB);
        int rem = idx - dyi * (XT * CINB);
        int xl = rem / CINB, cic = rem - xl * CINB;
        int gy = y + DIL * dyi - PAD;
        int gx = x0 - PAD + xl;
        short8 v = {0, 0, 0, 0, 0, 0, 0, 0};
        if ((unsigned)gy < (unsigned)WH && (unsigned)gx < (unsigned)WH)
            v = *(const short8*)&inb[((size_t)gy * WH + gx) * CIN + cic * 8];
        int r = dyi * XT + xl;
        int cs = (cic ^ ((r >> S) & (CINB - 1))) << 3;
        *(short8*)&T[r * CIN + cs] = v;
    }
    __syncthreads();

    const int w = tid >> 6, lane = tid & 63;
    const int l15 = lane & 15, loct = lane >> 4;
    int pxbase, ocbase;
    if (COUT == 16) { pxbase = w * 64; ocbase = 0; }
    else            { pxbase = (w >> 1) * 32; ocbase = (w & 1) * (OT * 16); }

    const short* wpb = wpack + (size_t)b * KPAD * COUT;
    f32x4 acc[OT][PT] = {};

    short8 A[OT];
    {
        size_t o = ((size_t)loct * COUT + ocbase + l15) * 8;
#pragma unroll
        for (int ot = 0; ot < OT; ++ot) A[ot] = *(const short8*)&wpb[o + ot * 128];
    }
    for (int s = 0; s < NSTEP; ++s) {
        short8 An[OT];
        if (s + 1 < NSTEP) {
            size_t o = ((size_t)((s + 1) * 4 + loct) * COUT + ocbase + l15) * 8;
#pragma unroll
            for (int ot = 0; ot < OT; ++ot) An[ot] = *(const short8*)&wpb[o + ot * 128];
        }
        int kq = s * 32 + (loct << 3);
        int pos = kq >> LC;
        if (pos > 24) pos = 24;                 // padded k: weights are zero
        int cic = (kq & (CIN - 1)) >> 3;
        int ky = pos / 5, kx = pos - ky * 5;
        int r = ky * XT + pxbase + l15 + kx * DIL;
        int cs = (cic ^ ((r >> S) & (CINB - 1))) << 3;
        int ba = r * CIN + cs;
        short8 Bv[PT];
#pragma unroll
        for (int pt = 0; pt < PT; ++pt) Bv[pt] = *(const short8*)&T[ba + pt * 16 * CIN];
#pragma unroll
        for (int ot = 0; ot < OT; ++ot)
#pragma unroll
            for (int pt = 0; pt < PT; ++pt)
                acc[ot][pt] = __builtin_amdgcn_mfma_f32_16x16x32_bf16(A[ot], Bv[pt], acc[ot][pt], 0, 0, 0);
#pragma unroll
        for (int ot = 0; ot < OT; ++ot) A[ot] = An[ot];
    }

#pragma unroll
    for (int ot = 0; ot < OT; ++ot)
#pragma unroll
        for (int pt = 0; pt < PT; ++pt) {
            int gpx = y * WH + x0 + pxbase + pt * 16 + l15;
            int oc = ocbase + ot * 16 + (loct << 2);
            *(f32x4*)&outp[((size_t)b * WH * WH + gpx) * COUT + oc] = acc[ot][pt];
        }
}

// ---------------- BN stats partials over NHWC fp32: part[b][32][2][C] ----------------
template<int C>
__global__ void stats_part(const float* __restrict__ z, float* __restrict__ part, int HW) {
    constexpr int C4 = C / 4;
    const int slice = blockIdx.x, b = blockIdx.y;
    const int PS = HW / 32;
    const int t = threadIdx.x;
    const int oc4 = t & (C4 - 1);
    f32x4 s4 = {0.f, 0.f, 0.f, 0.f}, q4 = {0.f, 0.f, 0.f, 0.f};
    for (int px = slice * PS + t / C4; px < (slice + 1) * PS; px += 256 / C4) {
        f32x4 v = *(const f32x4*)&z[((size_t)b * HW + px) * C + oc4 * 4];
        s4 += v; q4 += v * v;
    }
    __shared__ f32x4 ss[256], sq[256];
    ss[t] = s4; sq[t] = q4;
    __syncthreads();
    for (int off = 128; off >= C4; off >>= 1) {
        if (t < off) { ss[t] += ss[t + off]; sq[t] += sq[t + off]; }
        __syncthreads();
    }
    if (t < C4) {
        *(f32x4*)&part[((size_t)(b * 32 + slice) * 2 + 0) * C + t * 4] = ss[t];
        *(f32x4*)&part[((size_t)(b * 32 + slice) * 2 + 1) * C + t * 4] = sq[t];
    }
}

template<int C>
__global__ void stats_fin(const float* __restrict__ part, const float* __restrict__ s,
                          const float* __restrict__ bvec, float* __restrict__ ga,
                          float* __restrict__ be, int N) {
    int b = blockIdx.x, c = threadIdx.x;
    float S = 0.f, Q = 0.f;
    for (int j = 0; j < 32; ++j) {
        S += part[((size_t)(b * 32 + j) * 2 + 0) * C + c];
        Q += part[((size_t)(b * 32 + j) * 2 + 1) * C + c];
    }
    float inv = 1.f / (float)N;
    float m = S * inv;
    float var = Q * inv - m * m;
    float g = s[c] * rsqrtf(var + 1e-5f);
    ga[b * C + c] = g;
    be[b * C + c] = bvec[c] - m * g;
}

// ---------------- BN apply NHWC fp32 -> NHWC bf16 (optional ReLU) ----------------
template<int C, bool RELU>
__global__ void bn_apply_nhwc(const float* __restrict__ in, short* __restrict__ out,
                              const float* __restrict__ ga, const float* __restrict__ be,
                              int HW) {
    constexpr int C4 = C / 4;
    long total4 = (long)NB * HW * C4;
    long stride = (long)gridDim.x * blockDim.x;
    for (long i = (long)blockIdx.x * blockDim.x + threadIdx.x; i < total4; i += stride) {
        int c4 = (int)(i % C4);
        int b = (int)(i / ((long)HW * C4));
        f32x4 g = *(const f32x4*)&ga[b * C + c4 * 4];
        f32x4 e = *(const f32x4*)&be[b * C + c4 * 4];
        f32x4 v = *(const f32x4*)&in[i * 4];
        v = v * g + e;
        short4_ o;
#pragma unroll
        for (int j = 0; j < 4; ++j) {
            float f = v[j];
            if (RELU) f = fmaxf(f, 0.f);
            o[j] = tobf(f);
        }
        *(short4_*)&out[i * 4] = o;
    }
}

// ---------------- bn2 apply + 2x2 avgpool: c2 [B][65536][16] fp32 -> a2p [B][16384][16] bf16 ----------------
__global__ void bnpool(const float* __restrict__ in, short* __restrict__ out,
                       const float* __restrict__ ga, const float* __restrict__ be) {
    int t = blockIdx.x * 256 + threadIdx.x;   // 16*16384*4
    int c4 = t & 3, wo = (t >> 2) & 127, ho = (t >> 9) & 127, b = t >> 16;
    size_t pi = ((size_t)b * 65536 + (ho * 2) * 256 + wo * 2) * 16 + c4 * 4;
    f32x4 v = *(const f32x4*)&in[pi];
    v += *(const f32x4*)&in[pi + 16];
    v += *(const f32x4*)&in[pi + 4096];
    v += *(const f32x4*)&in[pi + 4112];
    f32x4 g = *(const f32x4*)&ga[b * 16 + c4 * 4];
    f32x4 e = *(const f32x4*)&be[b * 16 + c4 * 4];
    v = v * 0.25f * g + e;
    short4_ o;
#pragma unroll
    for (int j = 0; j < 4; ++j) o[j] = tobf(v[j]);
    *(short4_*)&out[((size_t)b * 16384 + ho * 128 + wo) * 16 + c4 * 4] = o;
}

// ---------------- conv7 1x1 64->4: a6 NHWC bf16 -> c7 NHWC fp32 [B][16384][4] ----------------
__global__ void conv7k(const short* __restrict__ a6, const float* __restrict__ w7g,
                       float* __restrict__ c7) {
    __shared__ float wsm[256];
    const int b = blockIdx.y;
    wsm[threadIdx.x] = w7g[b * 256 + threadIdx.x];
    __syncthreads();
    const int t = threadIdx.x;
    const int px = blockIdx.x * 64 + (t >> 2);
    const int part = t & 3;
    size_t base = ((size_t)b * 16384 + px) * 64 + part * 16;
    short8 s0 = *(const short8*)&a6[base];
    short8 s1 = *(const short8*)&a6[base + 8];
    f32x4 a = {0.f, 0.f, 0.f, 0.f};
#pragma unroll
    for (int ci = 0; ci < 8; ++ci) {
        float f0 = frombf(s0[ci]), f1 = frombf(s1[ci]);
#pragma unroll
        for (int o = 0; o < 4; ++o) {
            a[o] = fmaf(f0, wsm[o * 64 + part * 16 + ci], a[o]);
            a[o] = fmaf(f1, wsm[o * 64 + part * 16 + 8 + ci], a[o]);
        }
    }
#pragma unroll
    for (int o = 0; o < 4; ++o) {
        a[o] += __shfl_xor(a[o], 1);
        a[o] += __shfl_xor(a[o], 2);
    }
    if (part == 0) *(f32x4*)&c7[((size_t)b * 16384 + px) * 4] = a;
}

// ---------------- bilinear x2 (align_corners) from NHWC [B,128,128,4] + residual -> NCHW out ----------------
__global__ void up2_add(const float* __restrict__ h, const float* __restrict__ xin,
                        float* __restrict__ outp, int total) {
    int stride = gridDim.x * blockDim.x;
    const float sc = 127.f / 255.f;
    for (int i = blockIdx.x * blockDim.x + threadIdx.x; i < total; i += stride) {
        int xo = i & 255, yo = (i >> 8) & 255, c = (i >> 16) & 3, b = i >> 18;
        float px = xo * sc, py = yo * sc;
        int x0 = (int)px, y0 = (int)py;
        float fx = px - x0, fy = py - y0;
        int x1 = min(x0 + 1, 127), y1 = min(y0 + 1, 127);
        const float* hb = h + ((size_t)b << 16);
        float v00 = hb[((y0 << 7) + x0) * 4 + c], v01 = hb[((y0 << 7) + x1) * 4 + c];
        float v10 = hb[((y1 << 7) + x0) * 4 + c], v11 = hb[((y1 << 7) + x1) * 4 + c];
        float vt = v00 + (v01 - v00) * fx;
        float vb = v10 + (v11 - v10) * fx;
        outp[i] = vt + (vb - vt) * fy + xin[i];
    }
}

extern "C" void kernel_launch(void* const* d_in, const int* in_sizes, int n_in,
                              void* d_out, int out_size, void* d_ws, size_t ws_size,
                              hipStream_t stream) {
    const float* x = (const float*)d_in[0];
    const int* action = (const int*)d_in[1];
    const float *W[7], *Bi[7], *bns[7], *bnb[7];
    for (int i = 0; i < 7; ++i) { W[i]   = (const float*)d_in[2 + 2 * i];
                                  Bi[i]  = (const float*)d_in[3 + 2 * i]; }
    for (int i = 0; i < 7; ++i) { bns[i] = (const float*)d_in[16 + 2 * i];
                                  bnb[i] = (const float*)d_in[17 + 2 * i]; }
    float* out = (float*)d_out;

    // ---- workspace carve (bytes) ----
    char* p = (char*)d_ws;
    auto carve = [&](size_t bytes) { char* r = p; p += (bytes + 255) & ~(size_t)255; return r; };
    float* w1g  = (float*)carve(1600 * NB * 4);
    float* w7g  = (float*)carve(256 * NB * 4);
    float* ga   = (float*)carve(1024 * 4);
    float* be   = (float*)carve(1024 * 4);
    float* part = (float*)carve(16 * 32 * 2 * 64 * 4);
    short* wp2  = (short*)carve((size_t)416 * 16 * NB * 2);
    short* wp3  = (short*)carve((size_t)416 * 32 * NB * 2);
    short* wp4  = (short*)carve((size_t)800 * 32 * NB * 2);
    short* wp5  = (short*)carve((size_t)800 * 64 * NB * 2);
    short* wp6  = (short*)carve((size_t)1600 * 64 * NB * 2);
    float* CBUF = (float*)carve((size_t)NB * 65536 * 16 * 4);   // 67 MB: every conv out (fp32)
    short* AB0  = (short*)carve((size_t)NB * 16384 * 64 * 2);   // a0/a2p/a4/a6
    short* AB1  = (short*)carve((size_t)NB * 65536 * 16 * 2);   // a1/a3/a5

    // ---- weights ----
    gen_weights<<<dim3(7, NB), 256, 0, stream>>>(W[0], Bi[0], action, w1g, 1600);
    gen_weights<<<dim3(1, NB), 256, 0, stream>>>(W[6], Bi[6], action, w7g, 256);
    pack_w<16, 16><<<dim3(26, NB),  256, 0, stream>>>(W[1], Bi[1], action, wp2);
    pack_w<16, 32><<<dim3(52, NB),  256, 0, stream>>>(W[2], Bi[2], action, wp3);
    pack_w<32, 32><<<dim3(100, NB), 256, 0, stream>>>(W[3], Bi[3], action, wp4);
    pack_w<32, 64><<<dim3(200, NB), 256, 0, stream>>>(W[4], Bi[4], action, wp5);
    pack_w<64, 64><<<dim3(400, NB), 256, 0, stream>>>(W[5], Bi[5], action, wp6);

    // ---- bn0 -> a0 (NHWC bf16, C=4) ----
    bn_stats<<<64, 512, 0, stream>>>(x, bns[0], bnb[0], ga, be, 4, 65536);
    bn0_apply<<<4096, 256, 0, stream>>>(x, AB0, ga, be);

    // ---- conv1 -> CBUF; bn1+relu -> a1 ----
    conv1k<<<dim3(4, 64, NB), 256, 0, stream>>>(AB0, w1g, CBUF);
    stats_part<16><<<dim3(32, NB), 256, 0, stream>>>(CBUF, part, 65536);
    stats_fin<16><<<NB, 16, 0, stream>>>(part, bns[1], bnb[1], ga, be, 65536);
    bn_apply_nhwc<16, true><<<2048, 256, 0, stream>>>(CBUF, AB1, ga, be, 65536);

    // ---- conv2 -> CBUF; bn2 + avgpool -> a2p ----
    convmf<16, 16, 1, 256, 256><<<dim3(1, 256, NB), 256, 0, stream>>>(AB1, wp2, CBUF);
    stats_part<16><<<dim3(32, NB), 256, 0, stream>>>(CBUF, part, 65536);
    stats_fin<16><<<NB, 16, 0, stream>>>(part, bns[2], bnb[2], ga, be, 65536);
    bnpool<<<4096, 256, 0, stream>>>(CBUF, AB0, ga, be);

    // ---- conv3 -> CBUF; bn3+relu -> a3 ----
    convmf<16, 32, 2, 128, 64><<<dim3(2, 128, NB), 256, 0, stream>>>(AB0, wp3, CBUF);
    stats_part<32><<<dim3(32, NB), 256, 0, stream>>>(CBUF, part, 16384);
    stats_fin<32><<<NB, 32, 0, stream>>>(part, bns[3], bnb[3], ga, be, 16384);
    bn_apply_nhwc<32, true><<<2048, 256, 0, stream>>>(CBUF, AB1, ga, be, 16384);

    // ---- conv4 -> CBUF; bn4 -> a4 ----
    convmf<32, 32, 1, 128, 64><<<dim3(2, 128, NB), 256, 0, stream>>>(AB1, wp4, CBUF);
    stats_part<32><<<dim3(32, NB), 256, 0, stream>>>(CBUF, part, 16384);
    stats_fin<32><<<NB, 32, 0, stream>>>(part, bns[4], bnb[4], ga, be, 16384);
    bn_apply_nhwc<32, false><<<2048, 256, 0, stream>>>(CBUF, AB0, ga, be, 16384);

    // ---- conv5 -> CBUF; bn5+relu -> a5 ----
    convmf<32, 64, 2, 128, 64><<<dim3(2, 128, NB), 256, 0, stream>>>(AB0, wp5, CBUF);
    stats_part<64><<<dim3(32, NB), 256, 0, stream>>>(CBUF, part, 16384);
    stats_fin<64><<<NB, 64, 0, stream>>>(part, bns[5], bnb[5], ga, be, 16384);
    bn_apply_nhwc<64, true><<<2048, 256, 0, stream>>>(CBUF, AB1, ga, be, 16384);

    // ---- conv6 -> CBUF; bn6 -> a6 ----
    convmf<64, 64, 1, 128, 64><<<dim3(2, 128, NB), 256, 0, stream>>>(AB1, wp6, CBUF);
    stats_part<64><<<dim3(32, NB), 256, 0, stream>>>(CBUF, part, 16384);
    stats_fin<64><<<NB, 64, 0, stream>>>(part, bns[6], bnb[6], ga, be, 16384);
    bn_apply_nhwc<64, false><<<2048, 256, 0, stream>>>(CBUF, AB0, ga, be, 16384);

    // ---- conv7 -> CBUF (reused); up2 + residual -> out ----
    conv7k<<<dim3(256, NB), 256, 0, stream>>>(AB0, w7g, CBUF);
    up2_add<<<4096, 256, 0, stream>>>(CBUF, x, out, 4194304);
}

// Round 4
// 497.678 us; speedup vs baseline: 9.9154x; 1.0582x over previous
//
#include <hip/hip_runtime.h>

#define NB 16   // batch
#define NA 6    // actions

typedef __attribute__((ext_vector_type(8))) short short8;
typedef __attribute__((ext_vector_type(4))) short short4_;
typedef __attribute__((ext_vector_type(4))) float f32x4;

__device__ __forceinline__ short tobf(float f) {
    unsigned u = __builtin_bit_cast(unsigned, f);
    u += 0x7FFF + ((u >> 16) & 1);
    return (short)(u >> 16);
}
__device__ __forceinline__ float frombf(short s) {
    unsigned u = ((unsigned)(unsigned short)s) << 16;
    return __builtin_bit_cast(float, u);
}

// ---------------- weight gather (fp32, conv1/conv7) ----------------
__global__ void gen_weights(const float* __restrict__ w, const float* __restrict__ bias,
                            const int* __restrict__ action, float* __restrict__ out, int od) {
    int b = blockIdx.y;
    int a = action[b];
    for (int i = blockIdx.x * blockDim.x + threadIdx.x; i < od; i += gridDim.x * blockDim.x)
        out[(size_t)b * od + i] = w[(size_t)i * NA + a] + bias[i];
}

// ---------------- weight gather+pack to bf16 A-fragment layout [b][Kpad/8][COUT][8] ----------------
template<int CIN, int COUT>
__global__ void pack_w(const float* __restrict__ w, const float* __restrict__ bias,
                       const int* __restrict__ action, short* __restrict__ dst) {
    constexpr int KTOT = 25 * CIN;
    constexpr int KPAD = (KTOT + 31) & ~31;
    int b = blockIdx.y;
    int a = action[b];
    for (int j = blockIdx.x * 256 + threadIdx.x; j < COUT * KPAD; j += gridDim.x * 256) {
        int oc = j / KPAD, k = j - oc * KPAD;
        float v = 0.f;
        if (k < KTOT) {
            int pos = k / CIN, ci = k - pos * CIN;
            int ky = pos / 5, kx = pos - ky * 5;
            int od = ((oc * CIN + ci) * 5 + ky) * 5 + kx;
            v = w[(size_t)od * NA + a] + bias[od];
        }
        dst[((size_t)(b * (KPAD / 8) + (k >> 3)) * COUT + oc) * 8 + (k & 7)] = tobf(v);
    }
}

// ---------------- BN stats for bn0 (NCHW input x) ----------------
__global__ void bn_stats(const float* __restrict__ z, const float* __restrict__ s,
                         const float* __restrict__ bvec, float* __restrict__ ga,
                         float* __restrict__ be, int Cc, int N) {
    int bc = blockIdx.x;
    int c = bc % Cc;
    const float* p = z + (size_t)bc * N;
    float sum = 0.f, sq = 0.f;
    for (int i = threadIdx.x * 4; i < N; i += blockDim.x * 4) {
        float4 v = *(const float4*)(p + i);
        sum += (v.x + v.y) + (v.z + v.w);
        sq  += (v.x * v.x + v.y * v.y) + (v.z * v.z + v.w * v.w);
    }
#pragma unroll
    for (int off = 32; off > 0; off >>= 1) {
        sum += __shfl_down(sum, off);
        sq  += __shfl_down(sq, off);
    }
    __shared__ float ssum[8], ssq[8];
    int wv = threadIdx.x >> 6;
    if ((threadIdx.x & 63) == 0) { ssum[wv] = sum; ssq[wv] = sq; }
    __syncthreads();
    if (threadIdx.x == 0) {
        float S = 0.f, Q = 0.f;
        int nw = blockDim.x >> 6;
        for (int i = 0; i < nw; ++i) { S += ssum[i]; Q += ssq[i]; }
        float inv = 1.f / (float)N;
        float m = S * inv;
        float var = Q * inv - m * m;
        float g = s[c] * rsqrtf(var + 1e-5f);
        ga[bc] = g;
        be[bc] = bvec[c] - m * g;
    }
}

// ---------------- bn0 apply: x NCHW fp32 -> a0 NHWC bf16 (C=4) ----------------
__global__ void bn0_apply(const float* __restrict__ x, short* __restrict__ a0,
                          const float* __restrict__ ga, const float* __restrict__ be) {
    int t = blockIdx.x * 256 + threadIdx.x;
    int b = t >> 16, px = t & 65535;
    f32x4 g = *(const f32x4*)&ga[b * 4];
    f32x4 e = *(const f32x4*)&be[b * 4];
    short4_ o;
#pragma unroll
    for (int c = 0; c < 4; ++c) {
        float v = x[(((size_t)b * 4 + c) << 16) + px];
        o[c] = tobf(v * g[c] + e[c]);
    }
    *(short4_*)&a0[((size_t)t) * 4] = o;
}

// ---------------- conv1: one px/thread, 16 oc; LDS halo tile; bf16 out ----------------
__global__ void __launch_bounds__(256) conv1k(const short* __restrict__ a0,
                                              const float* __restrict__ w1g,
                                              short* __restrict__ c1) {
    __shared__ float wf[1600];          // [pos25][ci4][oc16]
    __shared__ short4_ tile[12 * 72];
    const int b = blockIdx.z;
    const int y0 = blockIdx.y * 4;
    const int x0 = blockIdx.x * 64;
    const int tid = threadIdx.x;
    for (int t = tid; t < 1600; t += 256) {
        int pos = t >> 6, ci = (t >> 4) & 3, oc = t & 15;
        wf[t] = w1g[b * 1600 + (oc * 4 + ci) * 25 + pos];
    }
    const short* ab = a0 + ((size_t)b << 18);
    for (int idx = tid; idx < 12 * 72; idx += 256) {
        int r = idx / 72, cl = idx - r * 72;
        int gy = y0 - 4 + r, gx = x0 - 4 + cl;
        short4_ v = {0, 0, 0, 0};
        if ((unsigned)gy < 256u && (unsigned)gx < 256u)
            v = *(const short4_*)&ab[(((size_t)gy << 8) + gx) << 2];
        tile[idx] = v;
    }
    __syncthreads();
    const int yr = tid >> 6, xc = tid & 63;
    f32x4 acc[4] = {};
#pragma unroll
    for (int ky = 0; ky < 5; ++ky) {
#pragma unroll
        for (int kx = 0; kx < 5; ++kx) {
            short4_ s = tile[(yr + 2 * ky) * 72 + xc + 2 * kx];
            const int pos = ky * 5 + kx;
#pragma unroll
            for (int ci = 0; ci < 4; ++ci) {
                float f = frombf(s[ci]);
                const float* wp = &wf[(pos * 4 + ci) * 16];
#pragma unroll
                for (int o = 0; o < 4; ++o)
                    acc[o] += *(const f32x4*)(wp + o * 4) * f;
            }
        }
    }
    size_t ob = ((size_t)b * 65536 + (size_t)(y0 + yr) * 256 + x0 + xc) * 16;
    short8 o0, o1;
#pragma unroll
    for (int j = 0; j < 4; ++j) {
        o0[j] = tobf(acc[0][j]); o0[4 + j] = tobf(acc[1][j]);
        o1[j] = tobf(acc[2][j]); o1[4 + j] = tobf(acc[3][j]);
    }
    *(short8*)&c1[ob] = o0;
    *(short8*)&c1[ob + 8] = o1;
}

// ---------------- BN stats over NHWC bf16 -> atomic part[b][2][C] ----------------
template<int C>
__global__ void stats_bf16(const short* __restrict__ z, float* __restrict__ part, int HW) {
    constexpr int C8 = C / 8;
    const int b = blockIdx.y;
    const int t = threadIdx.x;
    const size_t base = (size_t)b * HW * C;
    f32x4 s0 = {}, s1 = {}, q0 = {}, q1 = {};
    int total = HW * C8;
    int stride = gridDim.x * 256;
    for (int i = blockIdx.x * 256 + t; i < total; i += stride) {
        short8 v = *(const short8*)&z[base + (size_t)i * 8];
#pragma unroll
        for (int j = 0; j < 4; ++j) {
            float f0 = frombf(v[j]), f1 = frombf(v[4 + j]);
            s0[j] += f0; q0[j] += f0 * f0;
            s1[j] += f1; q1[j] += f1 * f1;
        }
    }
    __shared__ f32x4 SS[256][2], QQ[256][2];
    SS[t][0] = s0; SS[t][1] = s1; QQ[t][0] = q0; QQ[t][1] = q1;
    __syncthreads();
#pragma unroll
    for (int off = 128; off >= C8; off >>= 1) {
        if (t < off) {
            SS[t][0] += SS[t + off][0]; SS[t][1] += SS[t + off][1];
            QQ[t][0] += QQ[t + off][0]; QQ[t][1] += QQ[t + off][1];
        }
        __syncthreads();
    }
    if (t < C8) {
#pragma unroll
        for (int h = 0; h < 2; ++h)
#pragma unroll
            for (int j = 0; j < 4; ++j) {
                atomicAdd(&part[((size_t)b * 2 + 0) * C + t * 8 + h * 4 + j], SS[t][h][j]);
                atomicAdd(&part[((size_t)b * 2 + 1) * C + t * 8 + h * 4 + j], QQ[t][h][j]);
            }
    }
}

// ---------------- inline BN finalize for 8 channels ----------------
template<int C>
__device__ __forceinline__ void bn_fin8(const float* __restrict__ part,
                                        const float* __restrict__ sc,
                                        const float* __restrict__ bi,
                                        int b, int c0, float invN, f32x4* g, f32x4* e) {
#pragma unroll
    for (int h = 0; h < 2; ++h) {
        f32x4 Sv = *(const f32x4*)&part[((size_t)b * 2 + 0) * C + c0 + h * 4];
        f32x4 Qv = *(const f32x4*)&part[((size_t)b * 2 + 1) * C + c0 + h * 4];
        f32x4 scv = *(const f32x4*)&sc[c0 + h * 4];
        f32x4 biv = *(const f32x4*)&bi[c0 + h * 4];
#pragma unroll
        for (int j = 0; j < 4; ++j) {
            float m = Sv[j] * invN;
            float var = Qv[j] * invN - m * m;
            float gg = scv[j] * rsqrtf(var + 1e-5f);
            g[h][j] = gg;
            e[h][j] = biv[j] - m * gg;
        }
    }
}

// ---------------- BN apply bf16 -> bf16 (finalize inline) ----------------
template<int C, bool RELU>
__global__ void bn_apply2(const short* __restrict__ in, short* __restrict__ out,
                          const float* __restrict__ part, const float* __restrict__ sc,
                          const float* __restrict__ bi, int HW, float invN) {
    constexpr int C8 = C / 8;
    const int b = blockIdx.y;
    const int c8 = threadIdx.x & (C8 - 1);
    f32x4 g[2], e[2];
    bn_fin8<C>(part, sc, bi, b, c8 * 8, invN, g, e);
    const size_t base = (size_t)b * HW * C;
    int total = HW * C8;
    int stride = gridDim.x * 256;
    for (int i = blockIdx.x * 256 + threadIdx.x; i < total; i += stride) {
        short8 vin = *(const short8*)&in[base + (size_t)i * 8];
        short8 vout;
#pragma unroll
        for (int h = 0; h < 2; ++h)
#pragma unroll
            for (int j = 0; j < 4; ++j) {
                float f = frombf(vin[h * 4 + j]) * g[h][j] + e[h][j];
                if (RELU) f = fmaxf(f, 0.f);
                vout[h * 4 + j] = tobf(f);
            }
        *(short8*)&out[base + (size_t)i * 8] = vout;
    }
}

// ---------------- bn2 apply + 2x2 avgpool, bf16 -> bf16 (finalize inline) ----------------
__global__ void bnpool2(const short* __restrict__ in, short* __restrict__ out,
                        const float* __restrict__ part, const float* __restrict__ sc,
                        const float* __restrict__ bi) {
    const int b = blockIdx.y;
    const int c8 = threadIdx.x & 1;
    const int c0 = c8 * 8;
    f32x4 g[2], e[2];
    bn_fin8<16>(part, sc, bi, b, c0, 1.f / 65536.f, g, e);
    const size_t bin = (size_t)b * 65536 * 16;
    const size_t bout = (size_t)b * 16384 * 16;
    int total = 16384 * 2;
    int stride = gridDim.x * 256;
    for (int i = blockIdx.x * 256 + threadIdx.x; i < total; i += stride) {
        int opx = i >> 1;
        int ho = opx >> 7, wo = opx & 127;
        size_t p0 = bin + ((size_t)(ho * 2) * 256 + wo * 2) * 16 + c0;
        short8 v00 = *(const short8*)&in[p0];
        short8 v01 = *(const short8*)&in[p0 + 16];
        short8 v10 = *(const short8*)&in[p0 + 4096];
        short8 v11 = *(const short8*)&in[p0 + 4112];
        short8 vo;
#pragma unroll
        for (int h = 0; h < 2; ++h)
#pragma unroll
            for (int j = 0; j < 4; ++j) {
                int k = h * 4 + j;
                float f = (frombf(v00[k]) + frombf(v01[k]) + frombf(v10[k]) + frombf(v11[k])) * 0.25f;
                f = f * g[h][j] + e[h][j];
                vo[k] = tobf(f);
            }
        *(short8*)&out[bout + (size_t)i * 8] = vo;
    }
}

// ---------------- MFMA 5x5 conv v2: full unroll, max A-reuse, row pairs, fused stats ----------------
// in NHWC bf16 -> out NHWC bf16; part[b][2][COUT] atomic sums of out (fp32 acc)
template<int CIN, int COUT, int DIL, int WH, int PXB, int ROWS>
__global__ void __launch_bounds__(256) convmf2(const short* __restrict__ in,
                                               const short* __restrict__ wpack,
                                               short* __restrict__ outp,
                                               float* __restrict__ part) {
    constexpr int PAD   = 2 * DIL;
    constexpr int XT    = PXB + 4 * DIL + 1;
    constexpr int LROWS = (DIL == 1) ? (ROWS + 4) : 5;
    constexpr int KTOT  = 25 * CIN;
    constexpr int KPAD  = (KTOT + 31) & ~31;
    constexpr int NSTEP = KPAD / 32;
    constexpr int CINB  = CIN / 8;
    constexpr int S     = (CIN == 64) ? 0 : (CIN == 32) ? 1 : 2;
    constexpr int OT    = COUT / 16;            // wave covers ALL out-channels
    constexpr int BLKPX = ROWS * PXB;
    constexpr int PT    = BLKPX / 64;           // px tiles (of 16) per wave
    constexpr int LOGC  = (COUT == 64) ? 6 : (COUT == 32) ? 5 : 4;

    __shared__ short T[LROWS * XT * CIN];
    __shared__ float SP[4][2][COUT];

    const int b   = blockIdx.z;
    const int y0  = blockIdx.y * ROWS;
    const int x0  = blockIdx.x * PXB;
    const int tid = threadIdx.x;
    const short* inb = in + (size_t)b * WH * WH * CIN;

    for (int idx = tid; idx < LROWS * XT * CINB; idx += 256) {
        int dyi = idx / (XT * CINB);
        int rem = idx - dyi * (XT * CINB);
        int xl = rem / CINB, cic = rem - xl * CINB;
        int gy = (DIL == 1) ? (y0 + dyi - 2) : (y0 + 2 * dyi - 4);
        int gx = x0 - PAD + xl;
        short8 v = {};
        if ((unsigned)gy < (unsigned)WH && (unsigned)gx < (unsigned)WH)
            v = *(const short8*)&inb[((size_t)gy * WH + gx) * CIN + cic * 8];
        int r = dyi * XT + xl;
        int cs = (cic ^ ((r >> S) & (CINB - 1))) << 3;
        *(short8*)&T[r * CIN + cs] = v;
    }
    __syncthreads();

    const int w = tid >> 6, lane = tid & 63;
    const int l15 = lane & 15, loct = lane >> 4;
    const int hsel = loct >> 1;
    const int ro = (w * PT * 16) / PXB;
    const int xseg = (w * PT * 16) % PXB;
    const int rl = ro * XT + xseg + l15;        // lane's base LDS row index

    const short* wpb = wpack + (size_t)b * KPAD * COUT;
    const short* wl = wpb + ((size_t)loct * COUT + l15) * 8;
    f32x4 acc[OT][PT] = {};

#pragma unroll
    for (int s = 0; s < NSTEP; ++s) {
        short8 A[OT];
        const short* wls = wl + (size_t)s * (4 * COUT * 8);
#pragma unroll
        for (int ot = 0; ot < OT; ++ot)
            A[ot] = *(const short8*)&wls[ot * 16 * 8];
        int Cs, cic;
        if constexpr (CIN == 64) {
            constexpr int dummy = 0; (void)dummy;
            const int pos = s >> 1;               // compile-time after unroll
            Cs = (pos / 5) * XT + (pos % 5) * DIL;
            cic = (s & 1) * 4 + loct;
        } else if constexpr (CIN == 32) {
            const int pos = s;
            Cs = (pos / 5) * XT + (pos % 5) * DIL;
            cic = loct;
        } else {
            const int p0 = (2 * s > 24) ? 24 : 2 * s;
            const int p1 = (2 * s + 1 > 24) ? 24 : 2 * s + 1;
            const int C0 = (p0 / 5) * XT + (p0 % 5) * DIL;
            const int C1 = (p1 / 5) * XT + (p1 % 5) * DIL;
            Cs = hsel ? C1 : C0;
            cic = loct & 1;
        }
        short8 Bv[PT];
#pragma unroll
        for (int pt = 0; pt < PT; ++pt) {
            int r = rl + pt * 16 + Cs;
            int chunk = cic ^ ((r >> S) & (CINB - 1));
            Bv[pt] = *(const short8*)&T[r * CIN + (chunk << 3)];
        }
#pragma unroll
        for (int ot = 0; ot < OT; ++ot)
#pragma unroll
            for (int pt = 0; pt < PT; ++pt)
                acc[ot][pt] = __builtin_amdgcn_mfma_f32_16x16x32_bf16(A[ot], Bv[pt], acc[ot][pt], 0, 0, 0);
    }

    // ---- store bf16 ----
#pragma unroll
    for (int ot = 0; ot < OT; ++ot)
#pragma unroll
        for (int pt = 0; pt < PT; ++pt) {
            int gpx = (y0 + ro) * WH + x0 + xseg + pt * 16 + l15;
            int oc = ot * 16 + (loct << 2);
            short4_ o;
#pragma unroll
            for (int j = 0; j < 4; ++j) o[j] = tobf(acc[ot][pt][j]);
            *(short4_*)&outp[((size_t)b * WH * WH + gpx) * COUT + oc] = o;
        }

    // ---- fused BN stats ----
    float sv[OT][4], qv[OT][4];
#pragma unroll
    for (int ot = 0; ot < OT; ++ot)
#pragma unroll
        for (int j = 0; j < 4; ++j) {
            float sa = 0.f, qa = 0.f;
#pragma unroll
            for (int pt = 0; pt < PT; ++pt) { float v = acc[ot][pt][j]; sa += v; qa += v * v; }
#pragma unroll
            for (int m = 1; m <= 8; m <<= 1) { sa += __shfl_xor(sa, m); qa += __shfl_xor(qa, m); }
            sv[ot][j] = sa; qv[ot][j] = qa;
        }
    if (l15 == 0) {
#pragma unroll
        for (int ot = 0; ot < OT; ++ot)
#pragma unroll
            for (int j = 0; j < 4; ++j) {
                SP[w][0][ot * 16 + (loct << 2) + j] = sv[ot][j];
                SP[w][1][ot * 16 + (loct << 2) + j] = qv[ot][j];
            }
    }
    __syncthreads();
    if (tid < 2 * COUT) {
        int m = tid >> LOGC, c = tid & (COUT - 1);
        float v = SP[0][m][c] + SP[1][m][c] + SP[2][m][c] + SP[3][m][c];
        atomicAdd(&part[((size_t)b * 2 + m) * COUT + c], v);
    }
}

// ---------------- conv7 1x1 64->4: a6 NHWC bf16 -> c7 NHWC fp32 ----------------
__global__ void conv7k(const short* __restrict__ a6, const float* __restrict__ w7g,
                       float* __restrict__ c7) {
    __shared__ float wsm[256];
    const int b = blockIdx.y;
    wsm[threadIdx.x] = w7g[b * 256 + threadIdx.x];
    __syncthreads();
    const int t = threadIdx.x;
    const int px = blockIdx.x * 64 + (t >> 2);
    const int part = t & 3;
    size_t base = ((size_t)b * 16384 + px) * 64 + part * 16;
    short8 s0 = *(const short8*)&a6[base];
    short8 s1 = *(const short8*)&a6[base + 8];
    f32x4 a = {0.f, 0.f, 0.f, 0.f};
#pragma unroll
    for (int ci = 0; ci < 8; ++ci) {
        float f0 = frombf(s0[ci]), f1 = frombf(s1[ci]);
#pragma unroll
        for (int o = 0; o < 4; ++o) {
            a[o] = fmaf(f0, wsm[o * 64 + part * 16 + ci], a[o]);
            a[o] = fmaf(f1, wsm[o * 64 + part * 16 + 8 + ci], a[o]);
        }
    }
#pragma unroll
    for (int o = 0; o < 4; ++o) {
        a[o] += __shfl_xor(a[o], 1);
        a[o] += __shfl_xor(a[o], 2);
    }
    if (part == 0) *(f32x4*)&c7[((size_t)b * 16384 + px) * 4] = a;
}

// ---------------- bilinear x2 + residual -> NCHW out ----------------
__global__ void up2_add(const float* __restrict__ h, const float* __restrict__ xin,
                        float* __restrict__ outp, int total) {
    int stride = gridDim.x * blockDim.x;
    const float sc = 127.f / 255.f;
    for (int i = blockIdx.x * blockDim.x + threadIdx.x; i < total; i += stride) {
        int xo = i & 255, yo = (i >> 8) & 255, c = (i >> 16) & 3, b = i >> 18;
        float px = xo * sc, py = yo * sc;
        int x0 = (int)px, y0 = (int)py;
        float fx = px - x0, fy = py - y0;
        int x1 = min(x0 + 1, 127), y1 = min(y0 + 1, 127);
        const float* hb = h + ((size_t)b << 16);
        float v00 = hb[((y0 << 7) + x0) * 4 + c], v01 = hb[((y0 << 7) + x1) * 4 + c];
        float v10 = hb[((y1 << 7) + x0) * 4 + c], v11 = hb[((y1 << 7) + x1) * 4 + c];
        float vt = v00 + (v01 - v00) * fx;
        float vb = v10 + (v11 - v10) * fx;
        outp[i] = vt + (vb - vt) * fy + xin[i];
    }
}

extern "C" void kernel_launch(void* const* d_in, const int* in_sizes, int n_in,
                              void* d_out, int out_size, void* d_ws, size_t ws_size,
                              hipStream_t stream) {
    const float* x = (const float*)d_in[0];
    const int* action = (const int*)d_in[1];
    const float *W[7], *Bi[7], *bns[7], *bnb[7];
    for (int i = 0; i < 7; ++i) { W[i]   = (const float*)d_in[2 + 2 * i];
                                  Bi[i]  = (const float*)d_in[3 + 2 * i]; }
    for (int i = 0; i < 7; ++i) { bns[i] = (const float*)d_in[16 + 2 * i];
                                  bnb[i] = (const float*)d_in[17 + 2 * i]; }
    float* out = (float*)d_out;

    // ---- workspace carve (bytes) ----
    char* p = (char*)d_ws;
    auto carve = [&](size_t bytes) { char* r = p; p += (bytes + 255) & ~(size_t)255; return r; };
    float* w1g  = (float*)carve(1600 * NB * 4);
    float* w7g  = (float*)carve(256 * NB * 4);
    float* ga0  = (float*)carve(64 * 4);
    float* be0  = (float*)carve(64 * 4);
    // per-layer BN partial sums [b][2][C], atomically accumulated -> must be zeroed
    float* partAll = (float*)carve((size_t)NB * 2 * (16 + 16 + 32 + 32 + 64 + 64) * 4);
    float* p1 = partAll;                 // conv1, C=16
    float* p2 = p1 + NB * 2 * 16;        // conv2, C=16
    float* p3 = p2 + NB * 2 * 16;        // conv3, C=32
    float* p4 = p3 + NB * 2 * 32;        // conv4, C=32
    float* p5 = p4 + NB * 2 * 32;        // conv5, C=64
    float* p6 = p5 + NB * 2 * 64;        // conv6, C=64
    short* wp2  = (short*)carve((size_t)416 * 16 * NB * 2);
    short* wp3  = (short*)carve((size_t)416 * 32 * NB * 2);
    short* wp4  = (short*)carve((size_t)800 * 32 * NB * 2);
    short* wp5  = (short*)carve((size_t)800 * 64 * NB * 2);
    short* wp6  = (short*)carve((size_t)1600 * 64 * NB * 2);
    short* CBUF = (short*)carve((size_t)NB * 65536 * 16 * 2);   // 33.5 MB bf16 conv out
    short* AB0  = (short*)carve((size_t)NB * 16384 * 64 * 2);   // a0/a2p/a4/a6
    short* AB1  = (short*)carve((size_t)NB * 65536 * 16 * 2);   // a1/a3/a5
    float* C7   = (float*)carve((size_t)NB * 16384 * 4 * 4);

    hipMemsetAsync(partAll, 0, (size_t)NB * 2 * 224 * 4, stream);

    // ---- weights ----
    gen_weights<<<dim3(7, NB), 256, 0, stream>>>(W[0], Bi[0], action, w1g, 1600);
    gen_weights<<<dim3(1, NB), 256, 0, stream>>>(W[6], Bi[6], action, w7g, 256);
    pack_w<16, 16><<<dim3(26, NB),  256, 0, stream>>>(W[1], Bi[1], action, wp2);
    pack_w<16, 32><<<dim3(52, NB),  256, 0, stream>>>(W[2], Bi[2], action, wp3);
    pack_w<32, 32><<<dim3(100, NB), 256, 0, stream>>>(W[3], Bi[3], action, wp4);
    pack_w<32, 64><<<dim3(200, NB), 256, 0, stream>>>(W[4], Bi[4], action, wp5);
    pack_w<64, 64><<<dim3(400, NB), 256, 0, stream>>>(W[5], Bi[5], action, wp6);

    // ---- bn0 -> a0 ----
    bn_stats<<<64, 512, 0, stream>>>(x, bns[0], bnb[0], ga0, be0, 4, 65536);
    bn0_apply<<<4096, 256, 0, stream>>>(x, AB0, ga0, be0);

    // ---- conv1 -> CBUF bf16; stats; bn1+relu -> a1 ----
    conv1k<<<dim3(4, 64, NB), 256, 0, stream>>>(AB0, w1g, CBUF);
    stats_bf16<16><<<dim3(32, NB), 256, 0, stream>>>(CBUF, p1, 65536);
    bn_apply2<16, true><<<dim3(64, NB), 256, 0, stream>>>(CBUF, AB1, p1, bns[1], bnb[1], 65536, 1.f / 65536.f);

    // ---- conv2 -> CBUF + p2; bn2+pool -> a2p ----
    convmf2<16, 16, 1, 256, 128, 2><<<dim3(2, 128, NB), 256, 0, stream>>>(AB1, wp2, CBUF, p2);
    bnpool2<<<dim3(64, NB), 256, 0, stream>>>(CBUF, AB0, p2, bns[2], bnb[2]);

    // ---- conv3 -> CBUF + p3; bn3+relu -> a3 ----
    convmf2<16, 32, 2, 128, 128, 1><<<dim3(1, 128, NB), 256, 0, stream>>>(AB0, wp3, CBUF, p3);
    bn_apply2<32, true><<<dim3(64, NB), 256, 0, stream>>>(CBUF, AB1, p3, bns[3], bnb[3], 16384, 1.f / 16384.f);

    // ---- conv4 -> CBUF + p4; bn4 -> a4 ----
    convmf2<32, 32, 1, 128, 128, 2><<<dim3(1, 64, NB), 256, 0, stream>>>(AB1, wp4, CBUF, p4);
    bn_apply2<32, false><<<dim3(64, NB), 256, 0, stream>>>(CBUF, AB0, p4, bns[4], bnb[4], 16384, 1.f / 16384.f);

    // ---- conv5 -> CBUF + p5; bn5+relu -> a5 ----
    convmf2<32, 64, 2, 128, 128, 1><<<dim3(1, 128, NB), 256, 0, stream>>>(AB0, wp5, CBUF, p5);
    bn_apply2<64, true><<<dim3(64, NB), 256, 0, stream>>>(CBUF, AB1, p5, bns[5], bnb[5], 16384, 1.f / 16384.f);

    // ---- conv6 -> CBUF + p6; bn6 -> a6 ----
    convmf2<64, 64, 1, 128, 64, 2><<<dim3(2, 64, NB), 256, 0, stream>>>(AB1, wp6, CBUF, p6);
    bn_apply2<64, false><<<dim3(64, NB), 256, 0, stream>>>(CBUF, AB0, p6, bns[6], bnb[6], 16384, 1.f / 16384.f);

    // ---- conv7 -> C7; up2 + residual -> out ----
    conv7k<<<dim3(256, NB), 256, 0, stream>>>(AB0, w7g, C7);
    up2_add<<<4096, 256, 0, stream>>>(C7, x, out, 4194304);
}

// Round 5
// 387.967 us; speedup vs baseline: 12.7193x; 1.2828x over previous
//
#include <hip/hip_runtime.h>

#define NB 16   // batch
#define NA 6    // actions

typedef __attribute__((ext_vector_type(8))) short short8;
typedef __attribute__((ext_vector_type(4))) short short4_;
typedef __attribute__((ext_vector_type(4))) float f32x4;

__device__ __forceinline__ short tobf(float f) {
    unsigned u = __builtin_bit_cast(unsigned, f);
    u += 0x7FFF + ((u >> 16) & 1);
    return (short)(u >> 16);
}
__device__ __forceinline__ float frombf(short s) {
    unsigned u = ((unsigned)(unsigned short)s) << 16;
    return __builtin_bit_cast(float, u);
}

// ---------------- weight gather (fp32, conv1/conv7) ----------------
__global__ void gen_weights(const float* __restrict__ w, const float* __restrict__ bias,
                            const int* __restrict__ action, float* __restrict__ out, int od) {
    int b = blockIdx.y;
    int a = action[b];
    for (int i = blockIdx.x * blockDim.x + threadIdx.x; i < od; i += gridDim.x * blockDim.x)
        out[(size_t)b * od + i] = w[(size_t)i * NA + a] + bias[i];
}

// ---------------- weight gather+pack to bf16 A-fragment layout [b][Kpad/8][COUT][8] ----------------
template<int CIN, int COUT>
__global__ void pack_w(const float* __restrict__ w, const float* __restrict__ bias,
                       const int* __restrict__ action, short* __restrict__ dst) {
    constexpr int KTOT = 25 * CIN;
    constexpr int KPAD = (KTOT + 31) & ~31;
    int b = blockIdx.y;
    int a = action[b];
    for (int j = blockIdx.x * 256 + threadIdx.x; j < COUT * KPAD; j += gridDim.x * 256) {
        int oc = j / KPAD, k = j - oc * KPAD;
        float v = 0.f;
        if (k < KTOT) {
            int pos = k / CIN, ci = k - pos * CIN;
            int ky = pos / 5, kx = pos - ky * 5;
            int od = ((oc * CIN + ci) * 5 + ky) * 5 + kx;
            v = w[(size_t)od * NA + a] + bias[od];
        }
        dst[((size_t)(b * (KPAD / 8) + (k >> 3)) * COUT + oc) * 8 + (k & 7)] = tobf(v);
    }
}

// ---------------- BN stats for bn0 (NCHW input x) ----------------
__global__ void bn_stats(const float* __restrict__ z, const float* __restrict__ s,
                         const float* __restrict__ bvec, float* __restrict__ ga,
                         float* __restrict__ be, int Cc, int N) {
    int bc = blockIdx.x;
    int c = bc % Cc;
    const float* p = z + (size_t)bc * N;
    float sum = 0.f, sq = 0.f;
    for (int i = threadIdx.x * 4; i < N; i += blockDim.x * 4) {
        float4 v = *(const float4*)(p + i);
        sum += (v.x + v.y) + (v.z + v.w);
        sq  += (v.x * v.x + v.y * v.y) + (v.z * v.z + v.w * v.w);
    }
#pragma unroll
    for (int off = 32; off > 0; off >>= 1) {
        sum += __shfl_down(sum, off);
        sq  += __shfl_down(sq, off);
    }
    __shared__ float ssum[8], ssq[8];
    int wv = threadIdx.x >> 6;
    if ((threadIdx.x & 63) == 0) { ssum[wv] = sum; ssq[wv] = sq; }
    __syncthreads();
    if (threadIdx.x == 0) {
        float S = 0.f, Q = 0.f;
        int nw = blockDim.x >> 6;
        for (int i = 0; i < nw; ++i) { S += ssum[i]; Q += ssq[i]; }
        float inv = 1.f / (float)N;
        float m = S * inv;
        float var = Q * inv - m * m;
        float g = s[c] * rsqrtf(var + 1e-5f);
        ga[bc] = g;
        be[bc] = bvec[c] - m * g;
    }
}

// ---------------- bn0 apply: x NCHW fp32 -> a0 NHWC bf16 (C=4) ----------------
__global__ void bn0_apply(const float* __restrict__ x, short* __restrict__ a0,
                          const float* __restrict__ ga, const float* __restrict__ be) {
    int t = blockIdx.x * 256 + threadIdx.x;
    int b = t >> 16, px = t & 65535;
    f32x4 g = *(const f32x4*)&ga[b * 4];
    f32x4 e = *(const f32x4*)&be[b * 4];
    short4_ o;
#pragma unroll
    for (int c = 0; c < 4; ++c) {
        float v = x[(((size_t)b * 4 + c) << 16) + px];
        o[c] = tobf(v * g[c] + e[c]);
    }
    *(short4_*)&a0[((size_t)t) * 4] = o;
}

// ---------------- conv1: one px/thread, 16 oc; LDS halo tile; bf16 out ----------------
__global__ void __launch_bounds__(256) conv1k(const short* __restrict__ a0,
                                              const float* __restrict__ w1g,
                                              short* __restrict__ c1) {
    __shared__ float wf[1600];          // [pos25][ci4][oc16]
    __shared__ short4_ tile[12 * 72];
    const int b = blockIdx.z;
    const int y0 = blockIdx.y * 4;
    const int x0 = blockIdx.x * 64;
    const int tid = threadIdx.x;
    for (int t = tid; t < 1600; t += 256) {
        int pos = t >> 6, ci = (t >> 4) & 3, oc = t & 15;
        wf[t] = w1g[b * 1600 + (oc * 4 + ci) * 25 + pos];
    }
    const short* ab = a0 + ((size_t)b << 18);
    for (int idx = tid; idx < 12 * 72; idx += 256) {
        int r = idx / 72, cl = idx - r * 72;
        int gy = y0 - 4 + r, gx = x0 - 4 + cl;
        short4_ v = {0, 0, 0, 0};
        if ((unsigned)gy < 256u && (unsigned)gx < 256u)
            v = *(const short4_*)&ab[(((size_t)gy << 8) + gx) << 2];
        tile[idx] = v;
    }
    __syncthreads();
    const int yr = tid >> 6, xc = tid & 63;
    f32x4 acc[4] = {};
#pragma unroll
    for (int ky = 0; ky < 5; ++ky) {
#pragma unroll
        for (int kx = 0; kx < 5; ++kx) {
            short4_ s = tile[(yr + 2 * ky) * 72 + xc + 2 * kx];
            const int pos = ky * 5 + kx;
#pragma unroll
            for (int ci = 0; ci < 4; ++ci) {
                float f = frombf(s[ci]);
                const float* wp = &wf[(pos * 4 + ci) * 16];
#pragma unroll
                for (int o = 0; o < 4; ++o)
                    acc[o] += *(const f32x4*)(wp + o * 4) * f;
            }
        }
    }
    size_t ob = ((size_t)b * 65536 + (size_t)(y0 + yr) * 256 + x0 + xc) * 16;
    short8 o0, o1;
#pragma unroll
    for (int j = 0; j < 4; ++j) {
        o0[j] = tobf(acc[0][j]); o0[4 + j] = tobf(acc[1][j]);
        o1[j] = tobf(acc[2][j]); o1[4 + j] = tobf(acc[3][j]);
    }
    *(short8*)&c1[ob] = o0;
    *(short8*)&c1[ob + 8] = o1;
}

// ---------------- BN stats over NHWC bf16 -> atomic part[b][2][C] (conv1 only) ----------------
template<int C>
__global__ void stats_bf16(const short* __restrict__ z, float* __restrict__ part, int HW) {
    constexpr int C8 = C / 8;
    const int b = blockIdx.y;
    const int t = threadIdx.x;
    const size_t base = (size_t)b * HW * C;
    f32x4 s0 = {}, s1 = {}, q0 = {}, q1 = {};
    int total = HW * C8;
    int stride = gridDim.x * 256;
    for (int i = blockIdx.x * 256 + t; i < total; i += stride) {
        short8 v = *(const short8*)&z[base + (size_t)i * 8];
#pragma unroll
        for (int j = 0; j < 4; ++j) {
            float f0 = frombf(v[j]), f1 = frombf(v[4 + j]);
            s0[j] += f0; q0[j] += f0 * f0;
            s1[j] += f1; q1[j] += f1 * f1;
        }
    }
    __shared__ f32x4 SS[256][2], QQ[256][2];
    SS[t][0] = s0; SS[t][1] = s1; QQ[t][0] = q0; QQ[t][1] = q1;
    __syncthreads();
#pragma unroll
    for (int off = 128; off >= C8; off >>= 1) {
        if (t < off) {
            SS[t][0] += SS[t + off][0]; SS[t][1] += SS[t + off][1];
            QQ[t][0] += QQ[t + off][0]; QQ[t][1] += QQ[t + off][1];
        }
        __syncthreads();
    }
    if (t < C8) {
#pragma unroll
        for (int h = 0; h < 2; ++h)
#pragma unroll
            for (int j = 0; j < 4; ++j) {
                atomicAdd(&part[((size_t)b * 2 + 0) * C + t * 8 + h * 4 + j], SS[t][h][j]);
                atomicAdd(&part[((size_t)b * 2 + 1) * C + t * 8 + h * 4 + j], QQ[t][h][j]);
            }
    }
}

// ---------------- inline BN finalize for 8 channels (from part sums) ----------------
template<int C>
__device__ __forceinline__ void bn_fin8(const float* __restrict__ part,
                                        const float* __restrict__ sc,
                                        const float* __restrict__ bi,
                                        int b, int c0, float invN, f32x4* g, f32x4* e) {
#pragma unroll
    for (int h = 0; h < 2; ++h) {
        f32x4 Sv = *(const f32x4*)&part[((size_t)b * 2 + 0) * C + c0 + h * 4];
        f32x4 Qv = *(const f32x4*)&part[((size_t)b * 2 + 1) * C + c0 + h * 4];
        f32x4 scv = *(const f32x4*)&sc[c0 + h * 4];
        f32x4 biv = *(const f32x4*)&bi[c0 + h * 4];
#pragma unroll
        for (int j = 0; j < 4; ++j) {
            float m = Sv[j] * invN;
            float var = Qv[j] * invN - m * m;
            float gg = scv[j] * rsqrtf(var + 1e-5f);
            g[h][j] = gg;
            e[h][j] = biv[j] - m * gg;
        }
    }
}

// ---------------- bn2 apply + 2x2 avgpool, bf16 -> bf16 (finalize inline) ----------------
__global__ void bnpool2(const short* __restrict__ in, short* __restrict__ out,
                        const float* __restrict__ part, const float* __restrict__ sc,
                        const float* __restrict__ bi) {
    const int b = blockIdx.y;
    const int c8 = threadIdx.x & 1;
    const int c0 = c8 * 8;
    f32x4 g[2], e[2];
    bn_fin8<16>(part, sc, bi, b, c0, 1.f / 65536.f, g, e);
    const size_t bin = (size_t)b * 65536 * 16;
    const size_t bout = (size_t)b * 16384 * 16;
    int total = 16384 * 2;
    int stride = gridDim.x * 256;
    for (int i = blockIdx.x * 256 + threadIdx.x; i < total; i += stride) {
        int opx = i >> 1;
        int ho = opx >> 7, wo = opx & 127;
        size_t p0 = bin + ((size_t)(ho * 2) * 256 + wo * 2) * 16 + c0;
        short8 v00 = *(const short8*)&in[p0];
        short8 v01 = *(const short8*)&in[p0 + 16];
        short8 v10 = *(const short8*)&in[p0 + 4096];
        short8 v11 = *(const short8*)&in[p0 + 4112];
        short8 vo;
#pragma unroll
        for (int h = 0; h < 2; ++h)
#pragma unroll
            for (int j = 0; j < 4; ++j) {
                int k = h * 4 + j;
                float f = (frombf(v00[k]) + frombf(v01[k]) + frombf(v10[k]) + frombf(v11[k])) * 0.25f;
                f = f * g[h][j] + e[h][j];
                vo[k] = tobf(f);
            }
        *(short8*)&out[bout + (size_t)i * 8] = vo;
    }
}

// ---------------- MFMA 5x5 conv v3: 512 thr, prev-BN fused in staging, A prefetch, fused stats ----------------
// APPLY: 0 = none, 1 = affine, 2 = affine+relu (applied to staged input, in-bounds only)
template<int CIN, int COUT, int DIL, int WH, int PXB, int ROWS, int APPLY>
__global__ void __launch_bounds__(512) convmf3(const short* __restrict__ in,
                                               const short* __restrict__ wpack,
                                               short* __restrict__ outp,
                                               float* __restrict__ partout,
                                               const float* __restrict__ partin,
                                               const float* __restrict__ psc,
                                               const float* __restrict__ pbi,
                                               float invN) {
    constexpr int PAD   = 2 * DIL;
    constexpr int XT    = PXB + 4 * DIL + 1;
    constexpr int LROWS = (DIL == 1) ? (ROWS + 4) : 5;
    constexpr int KTOT  = 25 * CIN;
    constexpr int KPAD  = (KTOT + 31) & ~31;
    constexpr int NSTEP = KPAD / 32;
    constexpr int CINB  = CIN / 8;
    constexpr int S     = (CIN == 64) ? 0 : (CIN == 32) ? 1 : 2;
    constexpr int OCG   = (COUT == 16) ? 1 : 2;       // oc groups among 8 waves
    constexpr int PXG   = 8 / OCG;                    // px groups
    constexpr int OT    = COUT / 16 / OCG;            // oc tiles per wave
    constexpr int PT    = (ROWS * PXB) / (16 * PXG);  // px tiles per wave
    constexpr int LOGC  = (COUT == 64) ? 6 : (COUT == 32) ? 5 : 4;
    constexpr int TBYTES = LROWS * XT * CIN * 2;
    static_assert(PXG * 2 * COUT * 4 <= TBYTES, "SP alias fits in T");

    __shared__ __align__(16) char smem[TBYTES + 2 * CIN * 4];
    short* T  = (short*)smem;
    float* GA = (float*)(smem + TBYTES);
    float* BE = GA + CIN;
    float* SP = (float*)smem;                         // alias over T after barrier

    const int b   = blockIdx.z;
    const int y0  = blockIdx.y * ROWS;
    const int x0  = blockIdx.x * PXB;
    const int tid = threadIdx.x;

    if (APPLY) {
        if (tid < CIN) {
            float S0 = partin[((size_t)b * 2 + 0) * CIN + tid];
            float Q0 = partin[((size_t)b * 2 + 1) * CIN + tid];
            float m = S0 * invN;
            float var = Q0 * invN - m * m;
            float g = psc[tid] * rsqrtf(var + 1e-5f);
            GA[tid] = g;
            BE[tid] = pbi[tid] - m * g;
        }
        __syncthreads();
    }

    const short* inb = in + (size_t)b * WH * WH * CIN;
    for (int idx = tid; idx < LROWS * XT * CINB; idx += 512) {
        int dyi = idx / (XT * CINB);
        int rem = idx - dyi * (XT * CINB);
        int xl = rem / CINB, cic = rem - xl * CINB;
        int gy = (DIL == 1) ? (y0 + dyi - 2) : (y0 + 2 * dyi - 4);
        int gx = x0 - PAD + xl;
        short8 v = {};
        if ((unsigned)gy < (unsigned)WH && (unsigned)gx < (unsigned)WH) {
            v = *(const short8*)&inb[((size_t)gy * WH + gx) * CIN + cic * 8];
            if (APPLY) {
                f32x4 g0 = *(const f32x4*)&GA[cic * 8];
                f32x4 g1 = *(const f32x4*)&GA[cic * 8 + 4];
                f32x4 e0 = *(const f32x4*)&BE[cic * 8];
                f32x4 e1 = *(const f32x4*)&BE[cic * 8 + 4];
#pragma unroll
                for (int j = 0; j < 4; ++j) {
                    float f0 = frombf(v[j]) * g0[j] + e0[j];
                    float f1 = frombf(v[4 + j]) * g1[j] + e1[j];
                    if (APPLY == 2) { f0 = fmaxf(f0, 0.f); f1 = fmaxf(f1, 0.f); }
                    v[j] = tobf(f0); v[4 + j] = tobf(f1);
                }
            }
        }
        int r = dyi * XT + xl;
        int cs = (cic ^ ((r >> S) & (CINB - 1))) << 3;
        *(short8*)&T[r * CIN + cs] = v;
    }
    __syncthreads();

    const int w = tid >> 6, lane = tid & 63;
    const int l15 = lane & 15, loct = lane >> 4;
    const int ocg = w & (OCG - 1);
    const int pxg = w / OCG;
    const int ocbase = ocg * OT * 16;
    const int pxbase = pxg * PT * 16;
    const int ro = pxbase / PXB, xseg = pxbase % PXB;
    const int rl = ro * XT + xseg + l15;
    const int hsel = loct >> 1;

    const short* wl = wpack + (size_t)b * KPAD * COUT + ((size_t)loct * COUT + ocbase + l15) * 8;
    f32x4 acc[OT][PT] = {};

    short8 A[OT];
#pragma unroll
    for (int ot = 0; ot < OT; ++ot) A[ot] = *(const short8*)&wl[ot * 128];

#pragma unroll
    for (int s = 0; s < NSTEP; ++s) {
        short8 An[OT];
        if (s + 1 < NSTEP) {
            const short* wn = wl + (size_t)(s + 1) * (4 * COUT * 8);
#pragma unroll
            for (int ot = 0; ot < OT; ++ot) An[ot] = *(const short8*)&wn[ot * 128];
        }
        int Cs, cic;
        if constexpr (CIN == 64) {
            const int pos = s >> 1;
            Cs = (pos / 5) * XT + (pos % 5) * DIL;
            cic = (s & 1) * 4 + loct;
        } else if constexpr (CIN == 32) {
            const int pos = s;
            Cs = (pos / 5) * XT + (pos % 5) * DIL;
            cic = loct;
        } else {
            const int p0 = (2 * s > 24) ? 24 : 2 * s;
            const int p1 = (2 * s + 1 > 24) ? 24 : 2 * s + 1;
            const int C0 = (p0 / 5) * XT + (p0 % 5) * DIL;
            const int C1 = (p1 / 5) * XT + (p1 % 5) * DIL;
            Cs = hsel ? C1 : C0;
            cic = loct & 1;
        }
        short8 Bv[PT];
#pragma unroll
        for (int pt = 0; pt < PT; ++pt) {
            int r = rl + pt * 16 + Cs;
            int chunk = cic ^ ((r >> S) & (CINB - 1));
            Bv[pt] = *(const short8*)&T[r * CIN + (chunk << 3)];
        }
#pragma unroll
        for (int ot = 0; ot < OT; ++ot)
#pragma unroll
            for (int pt = 0; pt < PT; ++pt)
                acc[ot][pt] = __builtin_amdgcn_mfma_f32_16x16x32_bf16(A[ot], Bv[pt], acc[ot][pt], 0, 0, 0);
#pragma unroll
        for (int ot = 0; ot < OT; ++ot) A[ot] = An[ot];
    }

    // ---- store bf16 ----
#pragma unroll
    for (int ot = 0; ot < OT; ++ot)
#pragma unroll
        for (int pt = 0; pt < PT; ++pt) {
            int gpx = (y0 + ro) * WH + x0 + xseg + pt * 16 + l15;
            int oc = ocbase + ot * 16 + (loct << 2);
            short4_ o;
#pragma unroll
            for (int j = 0; j < 4; ++j) o[j] = tobf(acc[ot][pt][j]);
            *(short4_*)&outp[((size_t)b * WH * WH + gpx) * COUT + oc] = o;
        }

    __syncthreads();   // all waves done reading T -> safe to alias SP

    // ---- fused BN stats ----
    float sv[OT][4], qv[OT][4];
#pragma unroll
    for (int ot = 0; ot < OT; ++ot)
#pragma unroll
        for (int j = 0; j < 4; ++j) {
            float sa = 0.f, qa = 0.f;
#pragma unroll
            for (int pt = 0; pt < PT; ++pt) { float v = acc[ot][pt][j]; sa += v; qa += v * v; }
#pragma unroll
            for (int m = 1; m <= 8; m <<= 1) { sa += __shfl_xor(sa, m); qa += __shfl_xor(qa, m); }
            sv[ot][j] = sa; qv[ot][j] = qa;
        }
    if (l15 == 0) {
#pragma unroll
        for (int ot = 0; ot < OT; ++ot)
#pragma unroll
            for (int j = 0; j < 4; ++j) {
                int c = ocbase + ot * 16 + (loct << 2) + j;
                SP[(pxg * 2 + 0) * COUT + c] = sv[ot][j];
                SP[(pxg * 2 + 1) * COUT + c] = qv[ot][j];
            }
    }
    __syncthreads();
    if (tid < 2 * COUT) {
        int m = tid >> LOGC, c = tid & (COUT - 1);
        float v = 0.f;
#pragma unroll
        for (int g = 0; g < PXG; ++g) v += SP[(g * 2 + m) * COUT + c];
        atomicAdd(&partout[((size_t)b * 2 + m) * COUT + c], v);
    }
}

// ---------------- conv7 1x1 64->4 with bn6 fused: c6 raw bf16 -> c7 NHWC fp32 ----------------
__global__ void conv7k(const short* __restrict__ c6, const float* __restrict__ w7g,
                       const float* __restrict__ part, const float* __restrict__ sc,
                       const float* __restrict__ bi, float* __restrict__ c7) {
    __shared__ float wsm[256];
    __shared__ float GA[64], BE[64];
    const int b = blockIdx.y;
    const int t = threadIdx.x;
    wsm[t] = w7g[b * 256 + t];
    if (t < 64) {
        float S0 = part[((size_t)b * 2 + 0) * 64 + t];
        float Q0 = part[((size_t)b * 2 + 1) * 64 + t];
        float m = S0 * (1.f / 16384.f);
        float var = Q0 * (1.f / 16384.f) - m * m;
        float g = sc[t] * rsqrtf(var + 1e-5f);
        GA[t] = g;
        BE[t] = bi[t] - m * g;
    }
    __syncthreads();
    const int px = blockIdx.x * 64 + (t >> 2);
    const int q4 = t & 3;
    size_t base = ((size_t)b * 16384 + px) * 64 + q4 * 16;
    short8 s0 = *(const short8*)&c6[base];
    short8 s1 = *(const short8*)&c6[base + 8];
    f32x4 a = {0.f, 0.f, 0.f, 0.f};
#pragma unroll
    for (int ci = 0; ci < 8; ++ci) {
        float f0 = frombf(s0[ci]) * GA[q4 * 16 + ci] + BE[q4 * 16 + ci];
        float f1 = frombf(s1[ci]) * GA[q4 * 16 + 8 + ci] + BE[q4 * 16 + 8 + ci];
#pragma unroll
        for (int o = 0; o < 4; ++o) {
            a[o] = fmaf(f0, wsm[o * 64 + q4 * 16 + ci], a[o]);
            a[o] = fmaf(f1, wsm[o * 64 + q4 * 16 + 8 + ci], a[o]);
        }
    }
#pragma unroll
    for (int o = 0; o < 4; ++o) {
        a[o] += __shfl_xor(a[o], 1);
        a[o] += __shfl_xor(a[o], 2);
    }
    if (q4 == 0) *(f32x4*)&c7[((size_t)b * 16384 + px) * 4] = a;
}

// ---------------- bilinear x2 + residual -> NCHW out ----------------
__global__ void up2_add(const float* __restrict__ h, const float* __restrict__ xin,
                        float* __restrict__ outp, int total) {
    int stride = gridDim.x * blockDim.x;
    const float sc = 127.f / 255.f;
    for (int i = blockIdx.x * blockDim.x + threadIdx.x; i < total; i += stride) {
        int xo = i & 255, yo = (i >> 8) & 255, c = (i >> 16) & 3, b = i >> 18;
        float px = xo * sc, py = yo * sc;
        int x0 = (int)px, y0 = (int)py;
        float fx = px - x0, fy = py - y0;
        int x1 = min(x0 + 1, 127), y1 = min(y0 + 1, 127);
        const float* hb = h + ((size_t)b << 16);
        float v00 = hb[((y0 << 7) + x0) * 4 + c], v01 = hb[((y0 << 7) + x1) * 4 + c];
        float v10 = hb[((y1 << 7) + x0) * 4 + c], v11 = hb[((y1 << 7) + x1) * 4 + c];
        float vt = v00 + (v01 - v00) * fx;
        float vb = v10 + (v11 - v10) * fx;
        outp[i] = vt + (vb - vt) * fy + xin[i];
    }
}

extern "C" void kernel_launch(void* const* d_in, const int* in_sizes, int n_in,
                              void* d_out, int out_size, void* d_ws, size_t ws_size,
                              hipStream_t stream) {
    const float* x = (const float*)d_in[0];
    const int* action = (const int*)d_in[1];
    const float *W[7], *Bi[7], *bns[7], *bnb[7];
    for (int i = 0; i < 7; ++i) { W[i]   = (const float*)d_in[2 + 2 * i];
                                  Bi[i]  = (const float*)d_in[3 + 2 * i]; }
    for (int i = 0; i < 7; ++i) { bns[i] = (const float*)d_in[16 + 2 * i];
                                  bnb[i] = (const float*)d_in[17 + 2 * i]; }
    float* out = (float*)d_out;

    // ---- workspace carve (bytes) ----
    char* p = (char*)d_ws;
    auto carve = [&](size_t bytes) { char* r = p; p += (bytes + 255) & ~(size_t)255; return r; };
    float* w1g  = (float*)carve(1600 * NB * 4);
    float* w7g  = (float*)carve(256 * NB * 4);
    float* ga0  = (float*)carve(64 * 4);
    float* be0  = (float*)carve(64 * 4);
    float* partAll = (float*)carve((size_t)NB * 2 * 224 * 4);
    float* p1 = partAll;                 // conv1, C=16
    float* p2 = p1 + NB * 2 * 16;        // conv2, C=16
    float* p3 = p2 + NB * 2 * 16;        // conv3, C=32
    float* p4 = p3 + NB * 2 * 32;        // conv4, C=32
    float* p5 = p4 + NB * 2 * 32;        // conv5, C=64
    float* p6 = p5 + NB * 2 * 64;        // conv6, C=64
    short* wp2  = (short*)carve((size_t)416 * 16 * NB * 2);
    short* wp3  = (short*)carve((size_t)416 * 32 * NB * 2);
    short* wp4  = (short*)carve((size_t)800 * 32 * NB * 2);
    short* wp5  = (short*)carve((size_t)800 * 64 * NB * 2);
    short* wp6  = (short*)carve((size_t)1600 * 64 * NB * 2);
    short* CB_A = (short*)carve((size_t)NB * 65536 * 16 * 2);   // c1 / c3 / c5
    short* CB_B = (short*)carve((size_t)NB * 65536 * 16 * 2);   // c2 / c4 / c6
    short* A0   = (short*)carve((size_t)NB * 65536 * 4 * 2);    // a0, later a2p
    float* C7   = (float*)carve((size_t)NB * 16384 * 4 * 4);

    hipMemsetAsync(partAll, 0, (size_t)NB * 2 * 224 * 4, stream);

    // ---- weights ----
    gen_weights<<<dim3(7, NB), 256, 0, stream>>>(W[0], Bi[0], action, w1g, 1600);
    gen_weights<<<dim3(1, NB), 256, 0, stream>>>(W[6], Bi[6], action, w7g, 256);
    pack_w<16, 16><<<dim3(26, NB),  256, 0, stream>>>(W[1], Bi[1], action, wp2);
    pack_w<16, 32><<<dim3(52, NB),  256, 0, stream>>>(W[2], Bi[2], action, wp3);
    pack_w<32, 32><<<dim3(100, NB), 256, 0, stream>>>(W[3], Bi[3], action, wp4);
    pack_w<32, 64><<<dim3(200, NB), 256, 0, stream>>>(W[4], Bi[4], action, wp5);
    pack_w<64, 64><<<dim3(400, NB), 256, 0, stream>>>(W[5], Bi[5], action, wp6);

    // ---- bn0 -> a0 ----
    bn_stats<<<64, 512, 0, stream>>>(x, bns[0], bnb[0], ga0, be0, 4, 65536);
    bn0_apply<<<4096, 256, 0, stream>>>(x, A0, ga0, be0);

    // ---- conv1 -> c1 (CB_A) + p1 ----
    conv1k<<<dim3(4, 64, NB), 256, 0, stream>>>(A0, w1g, CB_A);
    stats_bf16<16><<<dim3(32, NB), 256, 0, stream>>>(CB_A, p1, 65536);

    // ---- conv2 (bn1+relu fused in staging) -> c2 (CB_B) + p2 ----
    convmf3<16, 16, 1, 256, 128, 2, 2><<<dim3(2, 128, NB), 512, 0, stream>>>(
        CB_A, wp2, CB_B, p2, p1, bns[1], bnb[1], 1.f / 65536.f);

    // ---- bn2 + avgpool -> a2p (A0) ----
    bnpool2<<<dim3(64, NB), 256, 0, stream>>>(CB_B, A0, p2, bns[2], bnb[2]);

    // ---- conv3 (input pre-normalized) -> c3 (CB_A) + p3 ----
    convmf3<16, 32, 2, 128, 128, 1, 0><<<dim3(1, 128, NB), 512, 0, stream>>>(
        A0, wp3, CB_A, p3, p2, bns[2], bnb[2], 1.f);

    // ---- conv4 (bn3+relu fused) -> c4 (CB_B) + p4 ----
    convmf3<32, 32, 1, 128, 128, 2, 2><<<dim3(1, 64, NB), 512, 0, stream>>>(
        CB_A, wp4, CB_B, p4, p3, bns[3], bnb[3], 1.f / 16384.f);

    // ---- conv5 (bn4 fused, no relu) -> c5 (CB_A) + p5 ----
    convmf3<32, 64, 2, 128, 128, 1, 1><<<dim3(1, 128, NB), 512, 0, stream>>>(
        CB_B, wp5, CB_A, p5, p4, bns[4], bnb[4], 1.f / 16384.f);

    // ---- conv6 (bn5+relu fused) -> c6 (CB_B) + p6 ----
    convmf3<64, 64, 1, 128, 64, 2, 2><<<dim3(2, 64, NB), 512, 0, stream>>>(
        CB_A, wp6, CB_B, p6, p5, bns[5], bnb[5], 1.f / 16384.f);

    // ---- conv7 (bn6 fused) -> C7; up2 + residual -> out ----
    conv7k<<<dim3(256, NB), 256, 0, stream>>>(CB_B, w7g, p6, bns[6], bnb[6], C7);
    up2_add<<<4096, 256, 0, stream>>>(C7, x, out, 4194304);
}

// Round 6
// 362.592 us; speedup vs baseline: 13.6094x; 1.0700x over previous
//
#include <hip/hip_runtime.h>

#define NB 16   // batch
#define NA 6    // actions

typedef __attribute__((ext_vector_type(8))) short short8;
typedef __attribute__((ext_vector_type(4))) short short4_;
typedef __attribute__((ext_vector_type(4))) float f32x4;
typedef __attribute__((ext_vector_type(4))) unsigned uint4_;
typedef __attribute__((ext_vector_type(2))) unsigned uint2_;

__device__ __forceinline__ short tobf(float f) {
    unsigned u = __builtin_bit_cast(unsigned, f);
    u += 0x7FFF + ((u >> 16) & 1);
    return (short)(u >> 16);
}
__device__ __forceinline__ float frombf(short s) {
    unsigned u = ((unsigned)(unsigned short)s) << 16;
    return __builtin_bit_cast(float, u);
}
// packed f32x2 -> bf16x2, RNE (single HW instruction)
__device__ __forceinline__ unsigned cvtpk(float a, float b) {
    unsigned r;
    asm("v_cvt_pk_bf16_f32 %0, %1, %2" : "=v"(r) : "v"(a), "v"(b));
    return r;
}

// ---------------- weight gather (fp32, conv1/conv7) ----------------
__global__ void gen_weights(const float* __restrict__ w, const float* __restrict__ bias,
                            const int* __restrict__ action, float* __restrict__ out, int od) {
    int b = blockIdx.y;
    int a = action[b];
    for (int i = blockIdx.x * blockDim.x + threadIdx.x; i < od; i += gridDim.x * blockDim.x)
        out[(size_t)b * od + i] = w[(size_t)i * NA + a] + bias[i];
}

// ---------------- weight gather+pack to bf16 A-fragment layout [b][Kpad/8][COUT][8] ----------------
template<int CIN, int COUT>
__global__ void pack_w(const float* __restrict__ w, const float* __restrict__ bias,
                       const int* __restrict__ action, short* __restrict__ dst) {
    constexpr int KTOT = 25 * CIN;
    constexpr int KPAD = (KTOT + 31) & ~31;
    int b = blockIdx.y;
    int a = action[b];
    for (int j = blockIdx.x * 256 + threadIdx.x; j < COUT * KPAD; j += gridDim.x * 256) {
        int oc = j / KPAD, k = j - oc * KPAD;
        float v = 0.f;
        if (k < KTOT) {
            int pos = k / CIN, ci = k - pos * CIN;
            int ky = pos / 5, kx = pos - ky * 5;
            int od = ((oc * CIN + ci) * 5 + ky) * 5 + kx;
            v = w[(size_t)od * NA + a] + bias[od];
        }
        dst[((size_t)(b * (KPAD / 8) + (k >> 3)) * COUT + oc) * 8 + (k & 7)] = tobf(v);
    }
}

// ---------------- BN stats for bn0 (NCHW input x) ----------------
__global__ void bn_stats(const float* __restrict__ z, const float* __restrict__ s,
                         const float* __restrict__ bvec, float* __restrict__ ga,
                         float* __restrict__ be, int Cc, int N) {
    int bc = blockIdx.x;
    int c = bc % Cc;
    const float* p = z + (size_t)bc * N;
    float sum = 0.f, sq = 0.f;
    for (int i = threadIdx.x * 4; i < N; i += blockDim.x * 4) {
        float4 v = *(const float4*)(p + i);
        sum += (v.x + v.y) + (v.z + v.w);
        sq  += (v.x * v.x + v.y * v.y) + (v.z * v.z + v.w * v.w);
    }
#pragma unroll
    for (int off = 32; off > 0; off >>= 1) {
        sum += __shfl_down(sum, off);
        sq  += __shfl_down(sq, off);
    }
    __shared__ float ssum[8], ssq[8];
    int wv = threadIdx.x >> 6;
    if ((threadIdx.x & 63) == 0) { ssum[wv] = sum; ssq[wv] = sq; }
    __syncthreads();
    if (threadIdx.x == 0) {
        float S = 0.f, Q = 0.f;
        int nw = blockDim.x >> 6;
        for (int i = 0; i < nw; ++i) { S += ssum[i]; Q += ssq[i]; }
        float inv = 1.f / (float)N;
        float m = S * inv;
        float var = Q * inv - m * m;
        float g = s[c] * rsqrtf(var + 1e-5f);
        ga[bc] = g;
        be[bc] = bvec[c] - m * g;
    }
}

// ---------------- bn0 apply: x NCHW fp32 -> a0 NHWC bf16 (C=4) ----------------
__global__ void bn0_apply(const float* __restrict__ x, short* __restrict__ a0,
                          const float* __restrict__ ga, const float* __restrict__ be) {
    int t = blockIdx.x * 256 + threadIdx.x;
    int b = t >> 16, px = t & 65535;
    f32x4 g = *(const f32x4*)&ga[b * 4];
    f32x4 e = *(const f32x4*)&be[b * 4];
    f32x4 f;
#pragma unroll
    for (int c = 0; c < 4; ++c)
        f[c] = x[(((size_t)b * 4 + c) << 16) + px] * g[c] + e[c];
    uint2_ o = {cvtpk(f[0], f[1]), cvtpk(f[2], f[3])};
    *(uint2_*)&a0[((size_t)t) * 4] = o;
}

// ---------------- conv1: one px/thread, 16 oc; LDS halo tile; bf16 out ----------------
__global__ void __launch_bounds__(256) conv1k(const short* __restrict__ a0,
                                              const float* __restrict__ w1g,
                                              short* __restrict__ c1) {
    __shared__ float wf[1600];          // [pos25][ci4][oc16]
    __shared__ short4_ tile[12 * 72];
    const int b = blockIdx.z;
    const int y0 = blockIdx.y * 4;
    const int x0 = blockIdx.x * 64;
    const int tid = threadIdx.x;
    for (int t = tid; t < 1600; t += 256) {
        int pos = t >> 6, ci = (t >> 4) & 3, oc = t & 15;
        wf[t] = w1g[b * 1600 + (oc * 4 + ci) * 25 + pos];
    }
    const short* ab = a0 + ((size_t)b << 18);
    for (int idx = tid; idx < 12 * 72; idx += 256) {
        int r = idx / 72, cl = idx - r * 72;
        int gy = y0 - 4 + r, gx = x0 - 4 + cl;
        short4_ v = {0, 0, 0, 0};
        if ((unsigned)gy < 256u && (unsigned)gx < 256u)
            v = *(const short4_*)&ab[(((size_t)gy << 8) + gx) << 2];
        tile[idx] = v;
    }
    __syncthreads();
    const int yr = tid >> 6, xc = tid & 63;
    f32x4 acc[4] = {};
#pragma unroll
    for (int ky = 0; ky < 5; ++ky) {
#pragma unroll
        for (int kx = 0; kx < 5; ++kx) {
            short4_ s = tile[(yr + 2 * ky) * 72 + xc + 2 * kx];
            const int pos = ky * 5 + kx;
#pragma unroll
            for (int ci = 0; ci < 4; ++ci) {
                float f = frombf(s[ci]);
                const float* wp = &wf[(pos * 4 + ci) * 16];
#pragma unroll
                for (int o = 0; o < 4; ++o)
                    acc[o] += *(const f32x4*)(wp + o * 4) * f;
            }
        }
    }
    size_t ob = ((size_t)b * 65536 + (size_t)(y0 + yr) * 256 + x0 + xc) * 16;
    uint4_ o0 = {cvtpk(acc[0][0], acc[0][1]), cvtpk(acc[0][2], acc[0][3]),
                 cvtpk(acc[1][0], acc[1][1]), cvtpk(acc[1][2], acc[1][3])};
    uint4_ o1 = {cvtpk(acc[2][0], acc[2][1]), cvtpk(acc[2][2], acc[2][3]),
                 cvtpk(acc[3][0], acc[3][1]), cvtpk(acc[3][2], acc[3][3])};
    *(uint4_*)&c1[ob] = o0;
    *(uint4_*)&c1[ob + 8] = o1;
}

// ---------------- BN stats over NHWC bf16 -> atomic part[b][2][C] (conv1 only) ----------------
template<int C>
__global__ void stats_bf16(const short* __restrict__ z, float* __restrict__ part, int HW) {
    constexpr int C8 = C / 8;
    const int b = blockIdx.y;
    const int t = threadIdx.x;
    const size_t base = (size_t)b * HW * C;
    f32x4 s0 = {}, s1 = {}, q0 = {}, q1 = {};
    int total = HW * C8;
    int stride = gridDim.x * 256;
    for (int i = blockIdx.x * 256 + t; i < total; i += stride) {
        short8 v = *(const short8*)&z[base + (size_t)i * 8];
#pragma unroll
        for (int j = 0; j < 4; ++j) {
            float f0 = frombf(v[j]), f1 = frombf(v[4 + j]);
            s0[j] += f0; q0[j] += f0 * f0;
            s1[j] += f1; q1[j] += f1 * f1;
        }
    }
    __shared__ f32x4 SS[256][2], QQ[256][2];
    SS[t][0] = s0; SS[t][1] = s1; QQ[t][0] = q0; QQ[t][1] = q1;
    __syncthreads();
#pragma unroll
    for (int off = 128; off >= C8; off >>= 1) {
        if (t < off) {
            SS[t][0] += SS[t + off][0]; SS[t][1] += SS[t + off][1];
            QQ[t][0] += QQ[t + off][0]; QQ[t][1] += QQ[t + off][1];
        }
        __syncthreads();
    }
    if (t < C8) {
#pragma unroll
        for (int h = 0; h < 2; ++h)
#pragma unroll
            for (int j = 0; j < 4; ++j) {
                atomicAdd(&part[((size_t)b * 2 + 0) * C + t * 8 + h * 4 + j], SS[t][h][j]);
                atomicAdd(&part[((size_t)b * 2 + 1) * C + t * 8 + h * 4 + j], QQ[t][h][j]);
            }
    }
}

// ---------------- inline BN finalize for 8 channels (from part sums) ----------------
template<int C>
__device__ __forceinline__ void bn_fin8(const float* __restrict__ part,
                                        const float* __restrict__ sc,
                                        const float* __restrict__ bi,
                                        int b, int c0, float invN, f32x4* g, f32x4* e) {
#pragma unroll
    for (int h = 0; h < 2; ++h) {
        f32x4 Sv = *(const f32x4*)&part[((size_t)b * 2 + 0) * C + c0 + h * 4];
        f32x4 Qv = *(const f32x4*)&part[((size_t)b * 2 + 1) * C + c0 + h * 4];
        f32x4 scv = *(const f32x4*)&sc[c0 + h * 4];
        f32x4 biv = *(const f32x4*)&bi[c0 + h * 4];
#pragma unroll
        for (int j = 0; j < 4; ++j) {
            float m = Sv[j] * invN;
            float var = Qv[j] * invN - m * m;
            float gg = scv[j] * rsqrtf(var + 1e-5f);
            g[h][j] = gg;
            e[h][j] = biv[j] - m * gg;
        }
    }
}

// ---------------- bn2 apply + 2x2 avgpool, bf16 -> bf16 (finalize inline) ----------------
__global__ void bnpool2(const short* __restrict__ in, short* __restrict__ out,
                        const float* __restrict__ part, const float* __restrict__ sc,
                        const float* __restrict__ bi) {
    const int b = blockIdx.y;
    const int c8 = threadIdx.x & 1;
    const int c0 = c8 * 8;
    f32x4 g[2], e[2];
    bn_fin8<16>(part, sc, bi, b, c0, 1.f / 65536.f, g, e);
    const size_t bin = (size_t)b * 65536 * 16;
    const size_t bout = (size_t)b * 16384 * 16;
    int total = 16384 * 2;
    int stride = gridDim.x * 256;
    for (int i = blockIdx.x * 256 + threadIdx.x; i < total; i += stride) {
        int opx = i >> 1;
        int ho = opx >> 7, wo = opx & 127;
        size_t p0 = bin + ((size_t)(ho * 2) * 256 + wo * 2) * 16 + c0;
        short8 v00 = *(const short8*)&in[p0];
        short8 v01 = *(const short8*)&in[p0 + 16];
        short8 v10 = *(const short8*)&in[p0 + 4096];
        short8 v11 = *(const short8*)&in[p0 + 4112];
        float f[8];
#pragma unroll
        for (int h = 0; h < 2; ++h)
#pragma unroll
            for (int j = 0; j < 4; ++j) {
                int k = h * 4 + j;
                float fv = (frombf(v00[k]) + frombf(v01[k]) + frombf(v10[k]) + frombf(v11[k])) * 0.25f;
                f[k] = fv * g[h][j] + e[h][j];
            }
        uint4_ vo = {cvtpk(f[0], f[1]), cvtpk(f[2], f[3]), cvtpk(f[4], f[5]), cvtpk(f[6], f[7])};
        *(uint4_*)&out[bout + (size_t)i * 8] = vo;
    }
}

// ---------------- MFMA 5x5 conv v4: retiled, cvt_pk, setprio, fused stats ----------------
// APPLY: 0 = none, 1 = affine, 2 = affine+relu (applied to staged input, in-bounds only)
template<int CIN, int COUT, int DIL, int WH, int PXB, int ROWS, int OCG, int APPLY>
__global__ void __launch_bounds__(512) convmf4(const short* __restrict__ in,
                                               const short* __restrict__ wpack,
                                               short* __restrict__ outp,
                                               float* __restrict__ partout,
                                               const float* __restrict__ partin,
                                               const float* __restrict__ psc,
                                               const float* __restrict__ pbi,
                                               float invN) {
    constexpr int PAD   = 2 * DIL;
    constexpr int XT    = PXB + 4 * DIL + 1;
    constexpr int LROWS = (DIL == 1) ? (ROWS + 4) : 5 * ROWS;
    constexpr int RSTR  = (DIL == 1) ? XT : 5 * XT;      // T-row stride per output row
    constexpr int KTOT  = 25 * CIN;
    constexpr int KPAD  = (KTOT + 31) & ~31;
    constexpr int NSTEP = KPAD / 32;
    constexpr int CINB  = CIN / 8;
    constexpr int S     = (CIN == 64) ? 0 : (CIN == 32) ? 1 : 2;
    constexpr int PXG   = 8 / OCG;
    constexpr int OT    = COUT / 16 / OCG;
    constexpr int PT    = ROWS * PXB / (16 * PXG);
    constexpr int LPXB  = (PXB == 32) ? 5 : (PXB == 64) ? 6 : 7;
    constexpr int LOGC  = (COUT == 64) ? 6 : (COUT == 32) ? 5 : 4;
    constexpr int TBYTES = LROWS * XT * CIN * 2;
    static_assert(PXG * 2 * COUT * 4 <= TBYTES, "SP alias fits in T");
    static_assert(PT * 16 <= ROWS * PXB, "pt range");

    __shared__ __align__(16) char smem[TBYTES + 2 * CIN * 4];
    short* T  = (short*)smem;
    float* GA = (float*)(smem + TBYTES);
    float* BE = GA + CIN;
    float* SP = (float*)smem;                            // alias over T after barrier

    const int b   = blockIdx.z;
    const int y0  = blockIdx.y * ROWS;
    const int x0  = blockIdx.x * PXB;
    const int tid = threadIdx.x;

    if (APPLY) {
        if (tid < CIN) {
            float S0 = partin[((size_t)b * 2 + 0) * CIN + tid];
            float Q0 = partin[((size_t)b * 2 + 1) * CIN + tid];
            float m = S0 * invN;
            float var = Q0 * invN - m * m;
            float g = psc[tid] * rsqrtf(var + 1e-5f);
            GA[tid] = g;
            BE[tid] = pbi[tid] - m * g;
        }
        __syncthreads();
    }

    const short* inb = in + (size_t)b * WH * WH * CIN;
    for (int idx = tid; idx < LROWS * XT * CINB; idx += 512) {
        int dyi = idx / (XT * CINB);
        int rem = idx - dyi * (XT * CINB);
        int xl = rem / CINB, cic = rem - xl * CINB;
        int gy;
        if (DIL == 1) gy = y0 + dyi - 2;
        else          gy = y0 + dyi / 5 + 2 * (dyi % 5) - 4;
        int gx = x0 - PAD + xl;
        short8 v = {};
        if ((unsigned)gy < (unsigned)WH && (unsigned)gx < (unsigned)WH) {
            v = *(const short8*)&inb[((size_t)gy * WH + gx) * CIN + cic * 8];
            if (APPLY) {
                float f[8];
#pragma unroll
                for (int j = 0; j < 8; ++j) f[j] = frombf(v[j]);
                f32x4 g0 = *(const f32x4*)&GA[cic * 8];
                f32x4 g1 = *(const f32x4*)&GA[cic * 8 + 4];
                f32x4 e0 = *(const f32x4*)&BE[cic * 8];
                f32x4 e1 = *(const f32x4*)&BE[cic * 8 + 4];
#pragma unroll
                for (int j = 0; j < 4; ++j) {
                    f[j]     = f[j]     * g0[j] + e0[j];
                    f[4 + j] = f[4 + j] * g1[j] + e1[j];
                    if (APPLY == 2) { f[j] = fmaxf(f[j], 0.f); f[4 + j] = fmaxf(f[4 + j], 0.f); }
                }
                uint4_ uv = {cvtpk(f[0], f[1]), cvtpk(f[2], f[3]),
                             cvtpk(f[4], f[5]), cvtpk(f[6], f[7])};
                v = __builtin_bit_cast(short8, uv);
            }
        }
        int r = dyi * XT + xl;
        int cs = (cic ^ ((r >> S) & (CINB - 1))) << 3;
        *(short8*)&T[r * CIN + cs] = v;
    }
    __syncthreads();

    const int w = tid >> 6, lane = tid & 63;
    const int l15 = lane & 15, loct = lane >> 4;
    const int ocg = w & (OCG - 1);
    const int pxg = w / OCG;
    const int ocbase = ocg * OT * 16;
    const int pxbase = pxg * PT * 16;
    const int hsel = loct >> 1;

    int bpt[PT];
#pragma unroll
    for (int pt = 0; pt < PT; ++pt) {
        int ppx = pxbase + pt * 16;
        bpt[pt] = (ppx >> LPXB) * RSTR + (ppx & (PXB - 1)) + l15;
    }

    const short* wl = wpack + (size_t)b * KPAD * COUT + ((size_t)loct * COUT + ocbase + l15) * 8;
    f32x4 acc[OT][PT] = {};

    short8 A[OT];
#pragma unroll
    for (int ot = 0; ot < OT; ++ot) A[ot] = *(const short8*)&wl[ot * 128];

    __builtin_amdgcn_s_setprio(1);
#pragma unroll
    for (int s = 0; s < NSTEP; ++s) {
        short8 An[OT];
        if (s + 1 < NSTEP) {
            const short* wn = wl + (size_t)(s + 1) * (4 * COUT * 8);
#pragma unroll
            for (int ot = 0; ot < OT; ++ot) An[ot] = *(const short8*)&wn[ot * 128];
        }
        int Cs, cic;
        if constexpr (CIN == 64) {
            const int pos = s >> 1;
            Cs = (pos / 5) * XT + (pos % 5) * DIL;
            cic = (s & 1) * 4 + loct;
        } else if constexpr (CIN == 32) {
            const int pos = s;
            Cs = (pos / 5) * XT + (pos % 5) * DIL;
            cic = loct;
        } else {
            const int p0 = (2 * s > 24) ? 24 : 2 * s;
            const int p1 = (2 * s + 1 > 24) ? 24 : 2 * s + 1;
            const int C0 = (p0 / 5) * XT + (p0 % 5) * DIL;
            const int C1 = (p1 / 5) * XT + (p1 % 5) * DIL;
            Cs = hsel ? C1 : C0;
            cic = loct & 1;
        }
        short8 Bv[PT];
#pragma unroll
        for (int pt = 0; pt < PT; ++pt) {
            int r = bpt[pt] + Cs;
            int chunk = cic ^ ((r >> S) & (CINB - 1));
            Bv[pt] = *(const short8*)&T[r * CIN + (chunk << 3)];
        }
#pragma unroll
        for (int ot = 0; ot < OT; ++ot)
#pragma unroll
            for (int pt = 0; pt < PT; ++pt)
                acc[ot][pt] = __builtin_amdgcn_mfma_f32_16x16x32_bf16(A[ot], Bv[pt], acc[ot][pt], 0, 0, 0);
#pragma unroll
        for (int ot = 0; ot < OT; ++ot) A[ot] = An[ot];
    }
    __builtin_amdgcn_s_setprio(0);

    // ---- store bf16 ----
#pragma unroll
    for (int ot = 0; ot < OT; ++ot)
#pragma unroll
        for (int pt = 0; pt < PT; ++pt) {
            int ppx = pxbase + pt * 16;
            int gpx = (y0 + (ppx >> LPXB)) * WH + x0 + (ppx & (PXB - 1)) + l15;
            int oc = ocbase + ot * 16 + (loct << 2);
            uint2_ st = {cvtpk(acc[ot][pt][0], acc[ot][pt][1]),
                         cvtpk(acc[ot][pt][2], acc[ot][pt][3])};
            *(uint2_*)&outp[((size_t)b * WH * WH + gpx) * COUT + oc] = st;
        }

    __syncthreads();   // all waves done reading T -> safe to alias SP

    // ---- fused BN stats ----
    float sv[OT][4], qv[OT][4];
#pragma unroll
    for (int ot = 0; ot < OT; ++ot)
#pragma unroll
        for (int j = 0; j < 4; ++j) {
            float sa = 0.f, qa = 0.f;
#pragma unroll
            for (int pt = 0; pt < PT; ++pt) { float v = acc[ot][pt][j]; sa += v; qa += v * v; }
#pragma unroll
            for (int m = 1; m <= 8; m <<= 1) { sa += __shfl_xor(sa, m); qa += __shfl_xor(qa, m); }
            sv[ot][j] = sa; qv[ot][j] = qa;
        }
    if (l15 == 0) {
#pragma unroll
        for (int ot = 0; ot < OT; ++ot)
#pragma unroll
            for (int j = 0; j < 4; ++j) {
                int c = ocbase + ot * 16 + (loct << 2) + j;
                SP[(pxg * 2 + 0) * COUT + c] = sv[ot][j];
                SP[(pxg * 2 + 1) * COUT + c] = qv[ot][j];
            }
    }
    __syncthreads();
    if (tid < 2 * COUT) {
        int m = tid >> LOGC, c = tid & (COUT - 1);
        float v = 0.f;
#pragma unroll
        for (int g = 0; g < PXG; ++g) v += SP[(g * 2 + m) * COUT + c];
        atomicAdd(&partout[((size_t)b * 2 + m) * COUT + c], v);
    }
}

// ---------------- conv7 1x1 64->4 with bn6 fused: c6 raw bf16 -> c7 NHWC fp32 ----------------
__global__ void conv7k(const short* __restrict__ c6, const float* __restrict__ w7g,
                       const float* __restrict__ part, const float* __restrict__ sc,
                       const float* __restrict__ bi, float* __restrict__ c7) {
    __shared__ float wsm[256];
    __shared__ float GA[64], BE[64];
    const int b = blockIdx.y;
    const int t = threadIdx.x;
    wsm[t] = w7g[b * 256 + t];
    if (t < 64) {
        float S0 = part[((size_t)b * 2 + 0) * 64 + t];
        float Q0 = part[((size_t)b * 2 + 1) * 64 + t];
        float m = S0 * (1.f / 16384.f);
        float var = Q0 * (1.f / 16384.f) - m * m;
        float g = sc[t] * rsqrtf(var + 1e-5f);
        GA[t] = g;
        BE[t] = bi[t] - m * g;
    }
    __syncthreads();
    const int px = blockIdx.x * 64 + (t >> 2);
    const int q4 = t & 3;
    size_t base = ((size_t)b * 16384 + px) * 64 + q4 * 16;
    short8 s0 = *(const short8*)&c6[base];
    short8 s1 = *(const short8*)&c6[base + 8];
    f32x4 a = {0.f, 0.f, 0.f, 0.f};
#pragma unroll
    for (int ci = 0; ci < 8; ++ci) {
        float f0 = frombf(s0[ci]) * GA[q4 * 16 + ci] + BE[q4 * 16 + ci];
        float f1 = frombf(s1[ci]) * GA[q4 * 16 + 8 + ci] + BE[q4 * 16 + 8 + ci];
#pragma unroll
        for (int o = 0; o < 4; ++o) {
            a[o] = fmaf(f0, wsm[o * 64 + q4 * 16 + ci], a[o]);
            a[o] = fmaf(f1, wsm[o * 64 + q4 * 16 + 8 + ci], a[o]);
        }
    }
#pragma unroll
    for (int o = 0; o < 4; ++o) {
        a[o] += __shfl_xor(a[o], 1);
        a[o] += __shfl_xor(a[o], 2);
    }
    if (q4 == 0) *(f32x4*)&c7[((size_t)b * 16384 + px) * 4] = a;
}

// ---------------- bilinear x2 + residual -> NCHW out ----------------
__global__ void up2_add(const float* __restrict__ h, const float* __restrict__ xin,
                        float* __restrict__ outp, int total) {
    int stride = gridDim.x * blockDim.x;
    const float sc = 127.f / 255.f;
    for (int i = blockIdx.x * blockDim.x + threadIdx.x; i < total; i += stride) {
        int xo = i & 255, yo = (i >> 8) & 255, c = (i >> 16) & 3, b = i >> 18;
        float px = xo * sc, py = yo * sc;
        int x0 = (int)px, y0 = (int)py;
        float fx = px - x0, fy = py - y0;
        int x1 = min(x0 + 1, 127), y1 = min(y0 + 1, 127);
        const float* hb = h + ((size_t)b << 16);
        float v00 = hb[((y0 << 7) + x0) * 4 + c], v01 = hb[((y0 << 7) + x1) * 4 + c];
        float v10 = hb[((y1 << 7) + x0) * 4 + c], v11 = hb[((y1 << 7) + x1) * 4 + c];
        float vt = v00 + (v01 - v00) * fx;
        float vb = v10 + (v11 - v10) * fx;
        outp[i] = vt + (vb - vt) * fy + xin[i];
    }
}

extern "C" void kernel_launch(void* const* d_in, const int* in_sizes, int n_in,
                              void* d_out, int out_size, void* d_ws, size_t ws_size,
                              hipStream_t stream) {
    const float* x = (const float*)d_in[0];
    const int* action = (const int*)d_in[1];
    const float *W[7], *Bi[7], *bns[7], *bnb[7];
    for (int i = 0; i < 7; ++i) { W[i]   = (const float*)d_in[2 + 2 * i];
                                  Bi[i]  = (const float*)d_in[3 + 2 * i]; }
    for (int i = 0; i < 7; ++i) { bns[i] = (const float*)d_in[16 + 2 * i];
                                  bnb[i] = (const float*)d_in[17 + 2 * i]; }
    float* out = (float*)d_out;

    // ---- workspace carve (bytes) ----
    char* p = (char*)d_ws;
    auto carve = [&](size_t bytes) { char* r = p; p += (bytes + 255) & ~(size_t)255; return r; };
    float* w1g  = (float*)carve(1600 * NB * 4);
    float* w7g  = (float*)carve(256 * NB * 4);
    float* ga0  = (float*)carve(64 * 4);
    float* be0  = (float*)carve(64 * 4);
    float* partAll = (float*)carve((size_t)NB * 2 * 224 * 4);
    float* p1 = partAll;                 // conv1, C=16
    float* p2 = p1 + NB * 2 * 16;        // conv2, C=16
    float* p3 = p2 + NB * 2 * 16;        // conv3, C=32
    float* p4 = p3 + NB * 2 * 32;        // conv4, C=32
    float* p5 = p4 + NB * 2 * 32;        // conv5, C=64
    float* p6 = p5 + NB * 2 * 64;        // conv6, C=64
    short* wp2  = (short*)carve((size_t)416 * 16 * NB * 2);
    short* wp3  = (short*)carve((size_t)416 * 32 * NB * 2);
    short* wp4  = (short*)carve((size_t)800 * 32 * NB * 2);
    short* wp5  = (short*)carve((size_t)800 * 64 * NB * 2);
    short* wp6  = (short*)carve((size_t)1600 * 64 * NB * 2);
    short* CB_A = (short*)carve((size_t)NB * 65536 * 16 * 2);   // c1 / c3 / c5
    short* CB_B = (short*)carve((size_t)NB * 65536 * 16 * 2);   // c2 / c4 / c6
    short* A0   = (short*)carve((size_t)NB * 65536 * 4 * 2);    // a0, later a2p
    float* C7   = (float*)carve((size_t)NB * 16384 * 4 * 4);

    hipMemsetAsync(partAll, 0, (size_t)NB * 2 * 224 * 4, stream);

    // ---- weights ----
    gen_weights<<<dim3(7, NB), 256, 0, stream>>>(W[0], Bi[0], action, w1g, 1600);
    gen_weights<<<dim3(1, NB), 256, 0, stream>>>(W[6], Bi[6], action, w7g, 256);
    pack_w<16, 16><<<dim3(26, NB),  256, 0, stream>>>(W[1], Bi[1], action, wp2);
    pack_w<16, 32><<<dim3(52, NB),  256, 0, stream>>>(W[2], Bi[2], action, wp3);
    pack_w<32, 32><<<dim3(100, NB), 256, 0, stream>>>(W[3], Bi[3], action, wp4);
    pack_w<32, 64><<<dim3(200, NB), 256, 0, stream>>>(W[4], Bi[4], action, wp5);
    pack_w<64, 64><<<dim3(400, NB), 256, 0, stream>>>(W[5], Bi[5], action, wp6);

    // ---- bn0 -> a0 ----
    bn_stats<<<64, 512, 0, stream>>>(x, bns[0], bnb[0], ga0, be0, 4, 65536);
    bn0_apply<<<4096, 256, 0, stream>>>(x, A0, ga0, be0);

    // ---- conv1 -> c1 (CB_A) + p1 ----
    conv1k<<<dim3(4, 64, NB), 256, 0, stream>>>(A0, w1g, CB_A);
    stats_bf16<16><<<dim3(32, NB), 256, 0, stream>>>(CB_A, p1, 65536);

    // ---- conv2 (bn1+relu fused in staging) -> c2 (CB_B) + p2 ----
    convmf4<16, 16, 1, 256, 32, 16, 1, 2><<<dim3(8, 16, NB), 512, 0, stream>>>(
        CB_A, wp2, CB_B, p2, p1, bns[1], bnb[1], 1.f / 65536.f);

    // ---- bn2 + avgpool -> a2p (A0) ----
    bnpool2<<<dim3(64, NB), 256, 0, stream>>>(CB_B, A0, p2, bns[2], bnb[2]);

    // ---- conv3 (input pre-normalized) -> c3 (CB_A) + p3 ----
    convmf4<16, 32, 2, 128, 128, 2, 1, 0><<<dim3(1, 64, NB), 512, 0, stream>>>(
        A0, wp3, CB_A, p3, p2, bns[2], bnb[2], 1.f);

    // ---- conv4 (bn3+relu fused) -> c4 (CB_B) + p4 ----
    convmf4<32, 32, 1, 128, 64, 4, 1, 2><<<dim3(2, 32, NB), 512, 0, stream>>>(
        CB_A, wp4, CB_B, p4, p3, bns[3], bnb[3], 1.f / 16384.f);

    // ---- conv5 (bn4 fused, no relu) -> c5 (CB_A) + p5 ----
    convmf4<32, 64, 2, 128, 128, 1, 2, 1><<<dim3(1, 128, NB), 512, 0, stream>>>(
        CB_B, wp5, CB_A, p5, p4, bns[4], bnb[4], 1.f / 16384.f);

    // ---- conv6 (bn5+relu fused) -> c6 (CB_B) + p6 ----
    convmf4<64, 64, 1, 128, 32, 4, 2, 2><<<dim3(4, 32, NB), 512, 0, stream>>>(
        CB_A, wp6, CB_B, p6, p5, bns[5], bnb[5], 1.f / 16384.f);

    // ---- conv7 (bn6 fused) -> C7; up2 + residual -> out ----
    conv7k<<<dim3(256, NB), 256, 0, stream>>>(CB_B, w7g, p6, bns[6], bnb[6], C7);
    up2_add<<<4096, 256, 0, stream>>>(C7, x, out, 4194304);
}

// Round 7
// 352.768 us; speedup vs baseline: 13.9884x; 1.0278x over previous
//
#include <hip/hip_runtime.h>

#define NB 16   // batch
#define NA 6    // actions

typedef __attribute__((ext_vector_type(8))) short short8;
typedef __attribute__((ext_vector_type(4))) short short4_;
typedef __attribute__((ext_vector_type(4))) float f32x4;
typedef __attribute__((ext_vector_type(4))) unsigned uint4_;
typedef __attribute__((ext_vector_type(2))) unsigned uint2_;

__device__ __forceinline__ short tobf(float f) {
    unsigned u = __builtin_bit_cast(unsigned, f);
    u += 0x7FFF + ((u >> 16) & 1);
    return (short)(u >> 16);
}
__device__ __forceinline__ float frombf(short s) {
    unsigned u = ((unsigned)(unsigned short)s) << 16;
    return __builtin_bit_cast(float, u);
}
// packed f32x2 -> bf16x2, RNE (single HW instruction)
__device__ __forceinline__ unsigned cvtpk(float a, float b) {
    unsigned r;
    asm("v_cvt_pk_bf16_f32 %0, %1, %2" : "=v"(r) : "v"(a), "v"(b));
    return r;
}

// ---------------- per-layer weight pack helper ----------------
template<int CIN, int COUT>
__device__ __forceinline__ void pack_one(const float* __restrict__ w, const float* __restrict__ bias,
                                         int a, int b, short* __restrict__ dst, int j) {
    constexpr int KTOT = 25 * CIN;
    constexpr int KPAD = (KTOT + 31) & ~31;
    if (j >= COUT * KPAD) return;
    int oc = j / KPAD, k = j - oc * KPAD;
    float v = 0.f;
    if (k < KTOT) {
        int pos = k / CIN, ci = k - pos * CIN;
        int ky = pos / 5, kx = pos - ky * 5;
        int od = ((oc * CIN + ci) * 5 + ky) * 5 + kx;
        v = w[(size_t)od * NA + a] + bias[od];
    }
    dst[((size_t)(b * (KPAD / 8) + (k >> 3)) * COUT + oc) * 8 + (k & 7)] = tobf(v);
}

// ---------------- ALL weight gather/pack in one launch ----------------
__global__ void pack_all(const float* __restrict__ w2, const float* __restrict__ b2,
                         const float* __restrict__ w3, const float* __restrict__ b3,
                         const float* __restrict__ w4, const float* __restrict__ b4,
                         const float* __restrict__ w5, const float* __restrict__ b5,
                         const float* __restrict__ w6, const float* __restrict__ b6,
                         const float* __restrict__ w1, const float* __restrict__ b1,
                         const float* __restrict__ w7, const float* __restrict__ b7,
                         const int* __restrict__ action,
                         short* __restrict__ d2, short* __restrict__ d3, short* __restrict__ d4,
                         short* __restrict__ d5, short* __restrict__ d6,
                         float* __restrict__ g1, float* __restrict__ g7) {
    const int b = blockIdx.y;
    const int a = action[b];
    const int bx = blockIdx.x;
    const int t = threadIdx.x;
    if (bx < 26)       pack_one<16, 16>(w2, b2, a, b, d2, bx * 256 + t);
    else if (bx < 78)  pack_one<16, 32>(w3, b3, a, b, d3, (bx - 26) * 256 + t);
    else if (bx < 178) pack_one<32, 32>(w4, b4, a, b, d4, (bx - 78) * 256 + t);
    else if (bx < 378) pack_one<32, 64>(w5, b5, a, b, d5, (bx - 178) * 256 + t);
    else if (bx < 778) pack_one<64, 64>(w6, b6, a, b, d6, (bx - 378) * 256 + t);
    else if (bx < 785) { int i = (bx - 778) * 256 + t;
                         if (i < 1600) g1[(size_t)b * 1600 + i] = w1[(size_t)i * NA + a] + b1[i]; }
    else               { g7[(size_t)b * 256 + t] = w7[(size_t)t * NA + a] + b7[t]; }
}

// ---------------- BN stats for bn0 (NCHW input x) ----------------
__global__ void bn_stats(const float* __restrict__ z, const float* __restrict__ s,
                         const float* __restrict__ bvec, float* __restrict__ ga,
                         float* __restrict__ be, int Cc, int N) {
    int bc = blockIdx.x;
    int c = bc % Cc;
    const float* p = z + (size_t)bc * N;
    float sum = 0.f, sq = 0.f;
    for (int i = threadIdx.x * 4; i < N; i += blockDim.x * 4) {
        float4 v = *(const float4*)(p + i);
        sum += (v.x + v.y) + (v.z + v.w);
        sq  += (v.x * v.x + v.y * v.y) + (v.z * v.z + v.w * v.w);
    }
#pragma unroll
    for (int off = 32; off > 0; off >>= 1) {
        sum += __shfl_down(sum, off);
        sq  += __shfl_down(sq, off);
    }
    __shared__ float ssum[8], ssq[8];
    int wv = threadIdx.x >> 6;
    if ((threadIdx.x & 63) == 0) { ssum[wv] = sum; ssq[wv] = sq; }
    __syncthreads();
    if (threadIdx.x == 0) {
        float S = 0.f, Q = 0.f;
        int nw = blockDim.x >> 6;
        for (int i = 0; i < nw; ++i) { S += ssum[i]; Q += ssq[i]; }
        float inv = 1.f / (float)N;
        float m = S * inv;
        float var = Q * inv - m * m;
        float g = s[c] * rsqrtf(var + 1e-5f);
        ga[bc] = g;
        be[bc] = bvec[c] - m * g;
    }
}

// ---------------- bn0 apply: x NCHW fp32 -> a0 NHWC bf16 (C=4) ----------------
__global__ void bn0_apply(const float* __restrict__ x, short* __restrict__ a0,
                          const float* __restrict__ ga, const float* __restrict__ be) {
    int t = blockIdx.x * 256 + threadIdx.x;
    int b = t >> 16, px = t & 65535;
    f32x4 g = *(const f32x4*)&ga[b * 4];
    f32x4 e = *(const f32x4*)&be[b * 4];
    f32x4 f;
#pragma unroll
    for (int c = 0; c < 4; ++c)
        f[c] = x[(((size_t)b * 4 + c) << 16) + px] * g[c] + e[c];
    uint2_ o = {cvtpk(f[0], f[1]), cvtpk(f[2], f[3])};
    *(uint2_*)&a0[((size_t)t) * 4] = o;
}

// ---------------- conv1: one px/thread, 16 oc; LDS halo tile; bf16 out ----------------
__global__ void __launch_bounds__(256) conv1k(const short* __restrict__ a0,
                                              const float* __restrict__ w1g,
                                              short* __restrict__ c1) {
    __shared__ float wf[1600];          // [pos25][ci4][oc16]
    __shared__ short4_ tile[12 * 72];
    const int b = blockIdx.z;
    const int y0 = blockIdx.y * 4;
    const int x0 = blockIdx.x * 64;
    const int tid = threadIdx.x;
    for (int t = tid; t < 1600; t += 256) {
        int pos = t >> 6, ci = (t >> 4) & 3, oc = t & 15;
        wf[t] = w1g[b * 1600 + (oc * 4 + ci) * 25 + pos];
    }
    const short* ab = a0 + ((size_t)b << 18);
    for (int idx = tid; idx < 12 * 72; idx += 256) {
        int r = idx / 72, cl = idx - r * 72;
        int gy = y0 - 4 + r, gx = x0 - 4 + cl;
        short4_ v = {0, 0, 0, 0};
        if ((unsigned)gy < 256u && (unsigned)gx < 256u)
            v = *(const short4_*)&ab[(((size_t)gy << 8) + gx) << 2];
        tile[idx] = v;
    }
    __syncthreads();
    const int yr = tid >> 6, xc = tid & 63;
    f32x4 acc[4] = {};
#pragma unroll
    for (int ky = 0; ky < 5; ++ky) {
#pragma unroll
        for (int kx = 0; kx < 5; ++kx) {
            short4_ s = tile[(yr + 2 * ky) * 72 + xc + 2 * kx];
            const int pos = ky * 5 + kx;
#pragma unroll
            for (int ci = 0; ci < 4; ++ci) {
                float f = frombf(s[ci]);
                const float* wp = &wf[(pos * 4 + ci) * 16];
#pragma unroll
                for (int o = 0; o < 4; ++o)
                    acc[o] += *(const f32x4*)(wp + o * 4) * f;
            }
        }
    }
    size_t ob = ((size_t)b * 65536 + (size_t)(y0 + yr) * 256 + x0 + xc) * 16;
    uint4_ o0 = {cvtpk(acc[0][0], acc[0][1]), cvtpk(acc[0][2], acc[0][3]),
                 cvtpk(acc[1][0], acc[1][1]), cvtpk(acc[1][2], acc[1][3])};
    uint4_ o1 = {cvtpk(acc[2][0], acc[2][1]), cvtpk(acc[2][2], acc[2][3]),
                 cvtpk(acc[3][0], acc[3][1]), cvtpk(acc[3][2], acc[3][3])};
    *(uint4_*)&c1[ob] = o0;
    *(uint4_*)&c1[ob + 8] = o1;
}

// ---------------- BN stats over NHWC bf16 -> atomic part[b][2][C] (conv1 only) ----------------
template<int C>
__global__ void stats_bf16(const short* __restrict__ z, float* __restrict__ part, int HW) {
    constexpr int C8 = C / 8;
    const int b = blockIdx.y;
    const int t = threadIdx.x;
    const size_t base = (size_t)b * HW * C;
    f32x4 s0 = {}, s1 = {}, q0 = {}, q1 = {};
    int total = HW * C8;
    int stride = gridDim.x * 256;
    for (int i = blockIdx.x * 256 + t; i < total; i += stride) {
        short8 v = *(const short8*)&z[base + (size_t)i * 8];
#pragma unroll
        for (int j = 0; j < 4; ++j) {
            float f0 = frombf(v[j]), f1 = frombf(v[4 + j]);
            s0[j] += f0; q0[j] += f0 * f0;
            s1[j] += f1; q1[j] += f1 * f1;
        }
    }
    __shared__ f32x4 SS[256][2], QQ[256][2];
    SS[t][0] = s0; SS[t][1] = s1; QQ[t][0] = q0; QQ[t][1] = q1;
    __syncthreads();
#pragma unroll
    for (int off = 128; off >= C8; off >>= 1) {
        if (t < off) {
            SS[t][0] += SS[t + off][0]; SS[t][1] += SS[t + off][1];
            QQ[t][0] += QQ[t + off][0]; QQ[t][1] += QQ[t + off][1];
        }
        __syncthreads();
    }
    if (t < C8) {
#pragma unroll
        for (int h = 0; h < 2; ++h)
#pragma unroll
            for (int j = 0; j < 4; ++j) {
                atomicAdd(&part[((size_t)b * 2 + 0) * C + t * 8 + h * 4 + j], SS[t][h][j]);
                atomicAdd(&part[((size_t)b * 2 + 1) * C + t * 8 + h * 4 + j], QQ[t][h][j]);
            }
    }
}

// ---------------- inline BN finalize for 8 channels (from part sums) ----------------
template<int C>
__device__ __forceinline__ void bn_fin8(const float* __restrict__ part,
                                        const float* __restrict__ sc,
                                        const float* __restrict__ bi,
                                        int b, int c0, float invN, f32x4* g, f32x4* e) {
#pragma unroll
    for (int h = 0; h < 2; ++h) {
        f32x4 Sv = *(const f32x4*)&part[((size_t)b * 2 + 0) * C + c0 + h * 4];
        f32x4 Qv = *(const f32x4*)&part[((size_t)b * 2 + 1) * C + c0 + h * 4];
        f32x4 scv = *(const f32x4*)&sc[c0 + h * 4];
        f32x4 biv = *(const f32x4*)&bi[c0 + h * 4];
#pragma unroll
        for (int j = 0; j < 4; ++j) {
            float m = Sv[j] * invN;
            float var = Qv[j] * invN - m * m;
            float gg = scv[j] * rsqrtf(var + 1e-5f);
            g[h][j] = gg;
            e[h][j] = biv[j] - m * gg;
        }
    }
}

// ---------------- bn2 apply + 2x2 avgpool, bf16 -> bf16 (finalize inline) ----------------
__global__ void bnpool2(const short* __restrict__ in, short* __restrict__ out,
                        const float* __restrict__ part, const float* __restrict__ sc,
                        const float* __restrict__ bi) {
    const int b = blockIdx.y;
    const int c8 = threadIdx.x & 1;
    const int c0 = c8 * 8;
    f32x4 g[2], e[2];
    bn_fin8<16>(part, sc, bi, b, c0, 1.f / 65536.f, g, e);
    const size_t bin = (size_t)b * 65536 * 16;
    const size_t bout = (size_t)b * 16384 * 16;
    int total = 16384 * 2;
    int stride = gridDim.x * 256;
    for (int i = blockIdx.x * 256 + threadIdx.x; i < total; i += stride) {
        int opx = i >> 1;
        int ho = opx >> 7, wo = opx & 127;
        size_t p0 = bin + ((size_t)(ho * 2) * 256 + wo * 2) * 16 + c0;
        short8 v00 = *(const short8*)&in[p0];
        short8 v01 = *(const short8*)&in[p0 + 16];
        short8 v10 = *(const short8*)&in[p0 + 4096];
        short8 v11 = *(const short8*)&in[p0 + 4112];
        float f[8];
#pragma unroll
        for (int h = 0; h < 2; ++h)
#pragma unroll
            for (int j = 0; j < 4; ++j) {
                int k = h * 4 + j;
                float fv = (frombf(v00[k]) + frombf(v01[k]) + frombf(v10[k]) + frombf(v11[k])) * 0.25f;
                f[k] = fv * g[h][j] + e[h][j];
            }
        uint4_ vo = {cvtpk(f[0], f[1]), cvtpk(f[2], f[3]), cvtpk(f[4], f[5]), cvtpk(f[6], f[7])};
        *(uint4_*)&out[bout + (size_t)i * 8] = vo;
    }
}

// ---------------- MFMA 5x5 conv v5: A 2-deep + B 1-deep register pipeline ----------------
// APPLY: 0 = none, 1 = affine, 2 = affine+relu (applied to staged input, in-bounds only)
template<int CIN, int COUT, int DIL, int WH, int PXB, int ROWS, int OCG, int APPLY>
__global__ void __launch_bounds__(512) convmf5(const short* __restrict__ in,
                                               const short* __restrict__ wpack,
                                               short* __restrict__ outp,
                                               float* __restrict__ partout,
                                               const float* __restrict__ partin,
                                               const float* __restrict__ psc,
                                               const float* __restrict__ pbi,
                                               float invN) {
    constexpr int PAD   = 2 * DIL;
    constexpr int XT    = PXB + 4 * DIL + 1;
    constexpr int LROWS = (DIL == 1) ? (ROWS + 4) : 5 * ROWS;
    constexpr int RSTR  = (DIL == 1) ? XT : 5 * XT;      // T-row stride per output row
    constexpr int KTOT  = 25 * CIN;
    constexpr int KPAD  = (KTOT + 31) & ~31;
    constexpr int NSTEP = KPAD / 32;
    constexpr int CINB  = CIN / 8;
    constexpr int S     = (CIN == 64) ? 0 : (CIN == 32) ? 1 : 2;
    constexpr int PXG   = 8 / OCG;
    constexpr int OT    = COUT / 16 / OCG;
    constexpr int PT    = ROWS * PXB / (16 * PXG);
    constexpr int LPXB  = (PXB == 32) ? 5 : (PXB == 64) ? 6 : 7;
    constexpr int LOGC  = (COUT == 64) ? 6 : (COUT == 32) ? 5 : 4;
    constexpr int TBYTES = LROWS * XT * CIN * 2;
    static_assert(PXG * 2 * COUT * 4 <= TBYTES, "SP alias fits in T");
    static_assert(NSTEP >= 2, "pipeline depth");

    __shared__ __align__(16) char smem[TBYTES + 2 * CIN * 4];
    short* T  = (short*)smem;
    float* GA = (float*)(smem + TBYTES);
    float* BE = GA + CIN;
    float* SP = (float*)smem;                            // alias over T after barrier

    const int b   = blockIdx.z;
    const int y0  = blockIdx.y * ROWS;
    const int x0  = blockIdx.x * PXB;
    const int tid = threadIdx.x;

    if (APPLY) {
        if (tid < CIN) {
            float S0 = partin[((size_t)b * 2 + 0) * CIN + tid];
            float Q0 = partin[((size_t)b * 2 + 1) * CIN + tid];
            float m = S0 * invN;
            float var = Q0 * invN - m * m;
            float g = psc[tid] * rsqrtf(var + 1e-5f);
            GA[tid] = g;
            BE[tid] = pbi[tid] - m * g;
        }
        __syncthreads();
    }

    const short* inb = in + (size_t)b * WH * WH * CIN;
    for (int idx = tid; idx < LROWS * XT * CINB; idx += 512) {
        int dyi = idx / (XT * CINB);
        int rem = idx - dyi * (XT * CINB);
        int xl = rem / CINB, cic = rem - xl * CINB;
        int gy;
        if (DIL == 1) gy = y0 + dyi - 2;
        else          gy = y0 + dyi / 5 + 2 * (dyi % 5) - 4;
        int gx = x0 - PAD + xl;
        short8 v = {};
        if ((unsigned)gy < (unsigned)WH && (unsigned)gx < (unsigned)WH) {
            v = *(const short8*)&inb[((size_t)gy * WH + gx) * CIN + cic * 8];
            if (APPLY) {
                float f[8];
#pragma unroll
                for (int j = 0; j < 8; ++j) f[j] = frombf(v[j]);
                f32x4 g0 = *(const f32x4*)&GA[cic * 8];
                f32x4 g1 = *(const f32x4*)&GA[cic * 8 + 4];
                f32x4 e0 = *(const f32x4*)&BE[cic * 8];
                f32x4 e1 = *(const f32x4*)&BE[cic * 8 + 4];
#pragma unroll
                for (int j = 0; j < 4; ++j) {
                    f[j]     = f[j]     * g0[j] + e0[j];
                    f[4 + j] = f[4 + j] * g1[j] + e1[j];
                    if (APPLY == 2) { f[j] = fmaxf(f[j], 0.f); f[4 + j] = fmaxf(f[4 + j], 0.f); }
                }
                uint4_ uv = {cvtpk(f[0], f[1]), cvtpk(f[2], f[3]),
                             cvtpk(f[4], f[5]), cvtpk(f[6], f[7])};
                v = __builtin_bit_cast(short8, uv);
            }
        }
        int r = dyi * XT + xl;
        int cs = (cic ^ ((r >> S) & (CINB - 1))) << 3;
        *(short8*)&T[r * CIN + cs] = v;
    }
    __syncthreads();

    const int w = tid >> 6, lane = tid & 63;
    const int l15 = lane & 15, loct = lane >> 4;
    const int ocg = w & (OCG - 1);
    const int pxg = w / OCG;
    const int ocbase = ocg * OT * 16;
    const int pxbase = pxg * PT * 16;
    const int hsel = loct >> 1;

    int bpt[PT];
#pragma unroll
    for (int pt = 0; pt < PT; ++pt) {
        int ppx = pxbase + pt * 16;
        bpt[pt] = (ppx >> LPXB) * RSTR + (ppx & (PXB - 1)) + l15;
    }

    const short* wl = wpack + (size_t)b * KPAD * COUT + ((size_t)loct * COUT + ocbase + l15) * 8;

    auto lA = [&](int s, short8* dst) {
        const short* ws = wl + (size_t)s * (4 * COUT * 8);
#pragma unroll
        for (int ot = 0; ot < OT; ++ot) dst[ot] = *(const short8*)&ws[ot * 128];
    };
    auto lB = [&](int s, short8* dst) {
        int Cs, cic;
        if constexpr (CIN == 64) {
            const int pos = s >> 1;
            Cs = (pos / 5) * XT + (pos % 5) * DIL;
            cic = (s & 1) * 4 + loct;
        } else if constexpr (CIN == 32) {
            Cs = (s / 5) * XT + (s % 5) * DIL;
            cic = loct;
        } else {
            const int p0 = (2 * s > 24) ? 24 : 2 * s;
            const int p1 = (2 * s + 1 > 24) ? 24 : 2 * s + 1;
            const int C0 = (p0 / 5) * XT + (p0 % 5) * DIL;
            const int C1 = (p1 / 5) * XT + (p1 % 5) * DIL;
            Cs = hsel ? C1 : C0;
            cic = loct & 1;
        }
#pragma unroll
        for (int pt = 0; pt < PT; ++pt) {
            int r = bpt[pt] + Cs;
            int chunk = cic ^ ((r >> S) & (CINB - 1));
            dst[pt] = *(const short8*)&T[r * CIN + (chunk << 3)];
        }
    };

    f32x4 acc[OT][PT] = {};
    short8 Acur[OT], Anx[OT], Bcur[PT];
    lA(0, Acur);
    lA(1, Anx);
    lB(0, Bcur);

    __builtin_amdgcn_s_setprio(1);
#pragma unroll
    for (int s = 0; s < NSTEP; ++s) {
        short8 An2[OT] = {}, Bn[PT] = {};
        if (s + 2 < NSTEP) lA(s + 2, An2);
        if (s + 1 < NSTEP) lB(s + 1, Bn);
#pragma unroll
        for (int ot = 0; ot < OT; ++ot)
#pragma unroll
            for (int pt = 0; pt < PT; ++pt)
                acc[ot][pt] = __builtin_amdgcn_mfma_f32_16x16x32_bf16(Acur[ot], Bcur[pt], acc[ot][pt], 0, 0, 0);
#pragma unroll
        for (int ot = 0; ot < OT; ++ot) { Acur[ot] = Anx[ot]; Anx[ot] = An2[ot]; }
#pragma unroll
        for (int pt = 0; pt < PT; ++pt) Bcur[pt] = Bn[pt];
    }
    __builtin_amdgcn_s_setprio(0);

    // ---- store bf16 ----
#pragma unroll
    for (int ot = 0; ot < OT; ++ot)
#pragma unroll
        for (int pt = 0; pt < PT; ++pt) {
            int ppx = pxbase + pt * 16;
            int gpx = (y0 + (ppx >> LPXB)) * WH + x0 + (ppx & (PXB - 1)) + l15;
            int oc = ocbase + ot * 16 + (loct << 2);
            uint2_ st = {cvtpk(acc[ot][pt][0], acc[ot][pt][1]),
                         cvtpk(acc[ot][pt][2], acc[ot][pt][3])};
            *(uint2_*)&outp[((size_t)b * WH * WH + gpx) * COUT + oc] = st;
        }

    __syncthreads();   // all waves done reading T -> safe to alias SP

    // ---- fused BN stats ----
    float sv[OT][4], qv[OT][4];
#pragma unroll
    for (int ot = 0; ot < OT; ++ot)
#pragma unroll
        for (int j = 0; j < 4; ++j) {
            float sa = 0.f, qa = 0.f;
#pragma unroll
            for (int pt = 0; pt < PT; ++pt) { float v = acc[ot][pt][j]; sa += v; qa += v * v; }
#pragma unroll
            for (int m = 1; m <= 8; m <<= 1) { sa += __shfl_xor(sa, m); qa += __shfl_xor(qa, m); }
            sv[ot][j] = sa; qv[ot][j] = qa;
        }
    if (l15 == 0) {
#pragma unroll
        for (int ot = 0; ot < OT; ++ot)
#pragma unroll
            for (int j = 0; j < 4; ++j) {
                int c = ocbase + ot * 16 + (loct << 2) + j;
                SP[(pxg * 2 + 0) * COUT + c] = sv[ot][j];
                SP[(pxg * 2 + 1) * COUT + c] = qv[ot][j];
            }
    }
    __syncthreads();
    if (tid < 2 * COUT) {
        int m = tid >> LOGC, c = tid & (COUT - 1);
        float v = 0.f;
#pragma unroll
        for (int g = 0; g < PXG; ++g) v += SP[(g * 2 + m) * COUT + c];
        atomicAdd(&partout[((size_t)b * 2 + m) * COUT + c], v);
    }
}

// ---------------- conv7 1x1 64->4 with bn6 fused: c6 raw bf16 -> c7 NHWC fp32 ----------------
__global__ void conv7k(const short* __restrict__ c6, const float* __restrict__ w7g,
                       const float* __restrict__ part, const float* __restrict__ sc,
                       const float* __restrict__ bi, float* __restrict__ c7) {
    __shared__ float wsm[256];
    __shared__ float GA[64], BE[64];
    const int b = blockIdx.y;
    const int t = threadIdx.x;
    wsm[t] = w7g[b * 256 + t];
    if (t < 64) {
        float S0 = part[((size_t)b * 2 + 0) * 64 + t];
        float Q0 = part[((size_t)b * 2 + 1) * 64 + t];
        float m = S0 * (1.f / 16384.f);
        float var = Q0 * (1.f / 16384.f) - m * m;
        float g = sc[t] * rsqrtf(var + 1e-5f);
        GA[t] = g;
        BE[t] = bi[t] - m * g;
    }
    __syncthreads();
    const int px = blockIdx.x * 64 + (t >> 2);
    const int q4 = t & 3;
    size_t base = ((size_t)b * 16384 + px) * 64 + q4 * 16;
    short8 s0 = *(const short8*)&c6[base];
    short8 s1 = *(const short8*)&c6[base + 8];
    f32x4 a = {0.f, 0.f, 0.f, 0.f};
#pragma unroll
    for (int ci = 0; ci < 8; ++ci) {
        float f0 = frombf(s0[ci]) * GA[q4 * 16 + ci] + BE[q4 * 16 + ci];
        float f1 = frombf(s1[ci]) * GA[q4 * 16 + 8 + ci] + BE[q4 * 16 + 8 + ci];
#pragma unroll
        for (int o = 0; o < 4; ++o) {
            a[o] = fmaf(f0, wsm[o * 64 + q4 * 16 + ci], a[o]);
            a[o] = fmaf(f1, wsm[o * 64 + q4 * 16 + 8 + ci], a[o]);
        }
    }
#pragma unroll
    for (int o = 0; o < 4; ++o) {
        a[o] += __shfl_xor(a[o], 1);
        a[o] += __shfl_xor(a[o], 2);
    }
    if (q4 == 0) *(f32x4*)&c7[((size_t)b * 16384 + px) * 4] = a;
}

// ---------------- bilinear x2 + residual -> NCHW out ----------------
__global__ void up2_add(const float* __restrict__ h, const float* __restrict__ xin,
                        float* __restrict__ outp, int total) {
    int stride = gridDim.x * blockDim.x;
    const float sc = 127.f / 255.f;
    for (int i = blockIdx.x * blockDim.x + threadIdx.x; i < total; i += stride) {
        int xo = i & 255, yo = (i >> 8) & 255, c = (i >> 16) & 3, b = i >> 18;
        float px = xo * sc, py = yo * sc;
        int x0 = (int)px, y0 = (int)py;
        float fx = px - x0, fy = py - y0;
        int x1 = min(x0 + 1, 127), y1 = min(y0 + 1, 127);
        const float* hb = h + ((size_t)b << 16);
        float v00 = hb[((y0 << 7) + x0) * 4 + c], v01 = hb[((y0 << 7) + x1) * 4 + c];
        float v10 = hb[((y1 << 7) + x0) * 4 + c], v11 = hb[((y1 << 7) + x1) * 4 + c];
        float vt = v00 + (v01 - v00) * fx;
        float vb = v10 + (v11 - v10) * fx;
        outp[i] = vt + (vb - vt) * fy + xin[i];
    }
}

extern "C" void kernel_launch(void* const* d_in, const int* in_sizes, int n_in,
                              void* d_out, int out_size, void* d_ws, size_t ws_size,
                              hipStream_t stream) {
    const float* x = (const float*)d_in[0];
    const int* action = (const int*)d_in[1];
    const float *W[7], *Bi[7], *bns[7], *bnb[7];
    for (int i = 0; i < 7; ++i) { W[i]   = (const float*)d_in[2 + 2 * i];
                                  Bi[i]  = (const float*)d_in[3 + 2 * i]; }
    for (int i = 0; i < 7; ++i) { bns[i] = (const float*)d_in[16 + 2 * i];
                                  bnb[i] = (const float*)d_in[17 + 2 * i]; }
    float* out = (float*)d_out;

    // ---- workspace carve (bytes) ----
    char* p = (char*)d_ws;
    auto carve = [&](size_t bytes) { char* r = p; p += (bytes + 255) & ~(size_t)255; return r; };
    float* w1g  = (float*)carve(1600 * NB * 4);
    float* w7g  = (float*)carve(256 * NB * 4);
    float* ga0  = (float*)carve(64 * 4);
    float* be0  = (float*)carve(64 * 4);
    float* partAll = (float*)carve((size_t)NB * 2 * 224 * 4);
    float* p1 = partAll;                 // conv1, C=16
    float* p2 = p1 + NB * 2 * 16;        // conv2, C=16
    float* p3 = p2 + NB * 2 * 16;        // conv3, C=32
    float* p4 = p3 + NB * 2 * 32;        // conv4, C=32
    float* p5 = p4 + NB * 2 * 32;        // conv5, C=64
    float* p6 = p5 + NB * 2 * 64;        // conv6, C=64
    short* wp2  = (short*)carve((size_t)416 * 16 * NB * 2);
    short* wp3  = (short*)carve((size_t)416 * 32 * NB * 2);
    short* wp4  = (short*)carve((size_t)800 * 32 * NB * 2);
    short* wp5  = (short*)carve((size_t)800 * 64 * NB * 2);
    short* wp6  = (short*)carve((size_t)1600 * 64 * NB * 2);
    short* CB_A = (short*)carve((size_t)NB * 65536 * 16 * 2);   // c1 / c3 / c5
    short* CB_B = (short*)carve((size_t)NB * 65536 * 16 * 2);   // c2 / c4 / c6
    short* A0   = (short*)carve((size_t)NB * 65536 * 4 * 2);    // a0, later a2p
    float* C7   = (float*)carve((size_t)NB * 16384 * 4 * 4);

    hipMemsetAsync(partAll, 0, (size_t)NB * 2 * 224 * 4, stream);

    // ---- all weight gather/pack in one launch ----
    pack_all<<<dim3(786, NB), 256, 0, stream>>>(
        W[1], Bi[1], W[2], Bi[2], W[3], Bi[3], W[4], Bi[4], W[5], Bi[5],
        W[0], Bi[0], W[6], Bi[6], action, wp2, wp3, wp4, wp5, wp6, w1g, w7g);

    // ---- bn0 -> a0 ----
    bn_stats<<<64, 512, 0, stream>>>(x, bns[0], bnb[0], ga0, be0, 4, 65536);
    bn0_apply<<<4096, 256, 0, stream>>>(x, A0, ga0, be0);

    // ---- conv1 -> c1 (CB_A) + p1 ----
    conv1k<<<dim3(4, 64, NB), 256, 0, stream>>>(A0, w1g, CB_A);
    stats_bf16<16><<<dim3(32, NB), 256, 0, stream>>>(CB_A, p1, 65536);

    // ---- conv2 (bn1+relu fused in staging) -> c2 (CB_B) + p2 ----
    convmf5<16, 16, 1, 256, 32, 16, 1, 2><<<dim3(8, 16, NB), 512, 0, stream>>>(
        CB_A, wp2, CB_B, p2, p1, bns[1], bnb[1], 1.f / 65536.f);

    // ---- bn2 + avgpool -> a2p (A0) ----
    bnpool2<<<dim3(64, NB), 256, 0, stream>>>(CB_B, A0, p2, bns[2], bnb[2]);

    // ---- conv3 (input pre-normalized) -> c3 (CB_A) + p3 ----
    convmf5<16, 32, 2, 128, 128, 2, 1, 0><<<dim3(1, 64, NB), 512, 0, stream>>>(
        A0, wp3, CB_A, p3, p2, bns[2], bnb[2], 1.f);

    // ---- conv4 (bn3+relu fused) -> c4 (CB_B) + p4 ----
    convmf5<32, 32, 1, 128, 64, 4, 1, 2><<<dim3(2, 32, NB), 512, 0, stream>>>(
        CB_A, wp4, CB_B, p4, p3, bns[3], bnb[3], 1.f / 16384.f);

    // ---- conv5 (bn4 fused, no relu) -> c5 (CB_A) + p5 ----
    convmf5<32, 64, 2, 128, 128, 1, 2, 1><<<dim3(1, 128, NB), 512, 0, stream>>>(
        CB_B, wp5, CB_A, p5, p4, bns[4], bnb[4], 1.f / 16384.f);

    // ---- conv6 (bn5+relu fused) -> c6 (CB_B) + p6 ----
    convmf5<64, 64, 1, 128, 32, 4, 2, 2><<<dim3(4, 32, NB), 512, 0, stream>>>(
        CB_A, wp6, CB_B, p6, p5, bns[5], bnb[5], 1.f / 16384.f);

    // ---- conv7 (bn6 fused) -> C7; up2 + residual -> out ----
    conv7k<<<dim3(256, NB), 256, 0, stream>>>(CB_B, w7g, p6, bns[6], bnb[6], C7);
    up2_add<<<4096, 256, 0, stream>>>(C7, x, out, 4194304);
}